// Round 11
// baseline (144.972 us; speedup 1.0000x reference)
//
#include <hip/hip_runtime.h>
#include <hip/hip_bf16.h>
#include <cstdint>

#define NHEADS 16
#define HDIM 64
#define BB 2
#define TSEQ 2048
#define DM 1024
#define MROWS (BB*TSEQ)   // 4096

typedef unsigned short u16;
typedef unsigned int u32;
typedef __bf16 bf16x8 __attribute__((ext_vector_type(8)));
typedef float f32x4 __attribute__((ext_vector_type(4)));

#define AS1C(p) ((const __attribute__((address_space(1))) u32*)(p))
#define AS3(p)  ((__attribute__((address_space(3))) u32*)(p))

static __device__ __forceinline__ u16 f2bf(float f) {
  return __builtin_bit_cast(u16, __float2bfloat16(f));
}
static __device__ __forceinline__ float bf2f(u16 u) {
  return __bfloat162float(__builtin_bit_cast(__hip_bfloat16, u));
}
// pack two non-NaN floats to bf16 pair (round-half-up, max rel err 2^-8)
static __device__ __forceinline__ u32 pack2bf(float a, float b) {
  const u32 ua = __builtin_bit_cast(u32, a) + 0x8000u;
  const u32 ub = __builtin_bit_cast(u32, b) + 0x8000u;
  return (ua >> 16) | (ub & 0xFFFF0000u);
}
static __device__ __forceinline__ f32x4 mfma16x16(bf16x8 a, bf16x8 b, f32x4 c) {
  return __builtin_amdgcn_mfma_f32_16x16x32_bf16(a, b, c, 0, 0, 0);
}

// ---------------- fused cast fp32 -> bf16 for x, W_qkv, W_o ----------------
#define N4_X   (MROWS * DM / 4)          // 1048576
#define N4_WQ  (3 * DM * DM / 4)         // 786432
#define N4_WO  (DM * DM / 4)             // 262144
__global__ __launch_bounds__(256) void cast_all(const float* __restrict__ x,
                                                const float* __restrict__ wq,
                                                const float* __restrict__ wo,
                                                u16* __restrict__ xb,
                                                u16* __restrict__ wqb,
                                                u16* __restrict__ wob) {
  int i = blockIdx.x * 256 + threadIdx.x;
  const int stride = gridDim.x * 256;
  for (; i < N4_X + N4_WQ + N4_WO; i += stride) {
    const float4* src; u16* dst; int j;
    if (i < N4_X)            { src = (const float4*)x;  dst = xb;  j = i; }
    else if (i < N4_X + N4_WQ) { src = (const float4*)wq; dst = wqb; j = i - N4_X; }
    else                     { src = (const float4*)wo; dst = wob; j = i - N4_X - N4_WQ; }
    float4 v = src[j];
    ushort4 o;
    o.x = f2bf(v.x); o.y = f2bf(v.y); o.z = f2bf(v.z); o.w = f2bf(v.w);
    ((ushort4*)dst)[j] = o;
  }
}

// ---------------- bf16 GEMM, C[m,n] = sum_k A[m,k]*B[n,k] ----------------
template<int WRITE_BF16>
__global__ __launch_bounds__(256, 2) void gemm_bt(const u16* __restrict__ A,
                                                  const u16* __restrict__ Bm,
                                                  float* __restrict__ Cf,
                                                  u16* __restrict__ Cb,
                                                  int M, int N, int K) {
  __shared__ u16 lA[2][128 * 32];
  __shared__ u16 lB[2][128 * 32];
  const int tid = threadIdx.x;
  const int w = tid >> 6, l = tid & 63;
  const int wr = w >> 1, wc = w & 1;
  int bid = blockIdx.y * gridDim.x + blockIdx.x;
  const int cpx = (gridDim.x * gridDim.y) >> 3;
  bid = (bid & 7) * cpx + (bid >> 3);
  const int bx = bid % gridDim.x, by = bid / gridDim.x;
  const int brow = by * 128, bcol = bx * 128;
  const int lr = l & 15, lg = l >> 4;

  const int srow = l >> 2;
  const int scol = (((l & 3) ^ (srow & 3)) * 8);  // pre-swizzled source k-offset

  auto stage = [&](int buf, int k0) {
#pragma unroll
    for (int is = 0; is < 2; ++is) {
      const int chunk = w * 2 + is;
      const int row = chunk * 16 + srow;
      __builtin_amdgcn_global_load_lds(AS1C(A + (size_t)(brow + row) * K + k0 + scol),
                                       AS3((char*)lA[buf] + chunk * 1024), 16, 0, 0);
      __builtin_amdgcn_global_load_lds(AS1C(Bm + (size_t)(bcol + row) * K + k0 + scol),
                                       AS3((char*)lB[buf] + chunk * 1024), 16, 0, 0);
    }
  };

  f32x4 acc[4][4] = {};
  const int nk = K >> 5;
  stage(0, 0);
  for (int kk = 0; kk < nk; ++kk) {
    const int cur = kk & 1;
    __syncthreads();
    if (kk + 1 < nk) stage(cur ^ 1, (kk + 1) << 5);
    bf16x8 af[4], bfr[4];
#pragma unroll
    for (int m = 0; m < 4; ++m) {
      const int row = wr * 64 + m * 16 + lr;
      const int sl = lg ^ (row & 3);
      af[m] = *(const bf16x8*)(&lA[cur][row * 32 + sl * 8]);
    }
#pragma unroll
    for (int n = 0; n < 4; ++n) {
      const int row = wc * 64 + n * 16 + lr;
      const int sl = lg ^ (row & 3);
      bfr[n] = *(const bf16x8*)(&lB[cur][row * 32 + sl * 8]);
    }
#pragma unroll
    for (int m = 0; m < 4; ++m)
#pragma unroll
      for (int n = 0; n < 4; ++n)
        acc[m][n] = mfma16x16(af[m], bfr[n], acc[m][n]);
  }
#pragma unroll
  for (int m = 0; m < 4; ++m)
#pragma unroll
    for (int n = 0; n < 4; ++n)
#pragma unroll
      for (int r = 0; r < 4; ++r) {
        const int row = brow + wr * 64 + m * 16 + lg * 4 + r;
        const int col = bcol + wc * 64 + n * 16 + lr;
        if constexpr (WRITE_BF16)
          Cb[(size_t)row * N + col] = f2bf(acc[m][n][r]);
        else
          Cf[(size_t)row * N + col] = acc[m][n][r];
      }
}

// ---------------- RoPE + reshape (vectorized, hw sin/cos) ----------------
// q pre-scaled by (1/8)*log2(e) so attention scores arrive in the log2
// domain. 16B loads/stores (8 cols/thread); v_fract+v_sin/v_cos replace libm
// sincosf (arg-reduction error ~1e-4 rad << bf16 rounding).
__global__ __launch_bounds__(256) void rope_reshape(const u16* __restrict__ qkvb,
                                                    u16* __restrict__ qb,
                                                    u16* __restrict__ kb,
                                                    u16* __restrict__ vbT) {
  const int bh = blockIdx.y;
  const int b = bh >> 4, h = bh & 15;
  const int t0 = blockIdx.x * 64;
  const int tid = threadIdx.x;
  const float C = -0.4152410118609203f;  // -log2(10000)/32
  const float QS = 0.125f * 1.44269504088896341f;
  const float R2PI = 0.15915494309189535f;

  for (int idx = tid; idx < 64 * 8; idx += 256) {
    const int tl = idx >> 3, grp = idx & 7;
    const int t = t0 + tl;
    const size_t base = ((size_t)(b * TSEQ + t)) * 3072 + h * 64 + grp * 8;
    u16 qv[8], kv8[8], qo[8], ko[8];
    *(uint4*)qv  = *(const uint4*)(qkvb + base);
    *(uint4*)kv8 = *(const uint4*)(qkvb + base + 1024);
#pragma unroll
    for (int j = 0; j < 4; ++j) {
      const int p = grp * 4 + j;
      const float inv = exp2f((float)p * C);
      const float rev = __builtin_amdgcn_fractf((float)t * inv * R2PI);
      const float sn = __builtin_amdgcn_sinf(rev);
      const float cs = __builtin_amdgcn_cosf(rev);
      const float qe = bf2f(qv[2 * j]), qoo = bf2f(qv[2 * j + 1]);
      const float ke = bf2f(kv8[2 * j]), koo = bf2f(kv8[2 * j + 1]);
      qo[2 * j]     = f2bf((qe * cs - qoo * sn) * QS);
      qo[2 * j + 1] = f2bf((qe * sn + qoo * cs) * QS);
      ko[2 * j]     = f2bf(ke * cs - koo * sn);
      ko[2 * j + 1] = f2bf(ke * sn + koo * cs);
    }
    const size_t obase = ((size_t)bh * TSEQ + t) * 64 + grp * 8;
    *(uint4*)(qb + obase) = *(uint4*)qo;
    *(uint4*)(kb + obase) = *(uint4*)ko;
  }

  __shared__ u16 lT[64][65];
  for (int idx = tid; idx < 64 * 64; idx += 256) {
    const int tl = idx >> 6, d = idx & 63;
    lT[tl][d] = qkvb[((size_t)(b * TSEQ + t0 + tl)) * 3072 + 2048 + h * 64 + d];
  }
  __syncthreads();
  for (int idx = tid; idx < 64 * 64; idx += 256) {
    const int d = idx >> 6, tl = idx & 63;
    vbT[((size_t)bh * 64 + d) * TSEQ + t0 + tl] = lT[tl][d];
  }
}

// ---------------- causal flash attention (R5 skeleton, V direct from L2) ---
// R5 structure (proven best): 512 blocks x 512 thr (8 waves = 4 q-waves x
// 2 kv-groups), 2 blocks/CU, uniform q-tile pair {pair, 31-pair} = 33
// kv-tiles/block. Change vs R5: V is NOT staged in LDS — V per head (256KB)
// is L2-resident on its XCD, so vf fragments load directly global->VGPR,
// issued at the top of each tile's compute (~400cyc of QK^T+softmax hides
// the ~200cyc L2 latency). Removes 8/18 of per-iter DS ops and half the
// global_load_lds traffic; LDS 80KB -> 48KB.
__global__ __launch_bounds__(512, 2) void attn_fwd(const u16* __restrict__ qb,
                                                   const u16* __restrict__ kb,
                                                   const u16* __restrict__ vbT,
                                                   u16* __restrict__ ob) {
  __shared__ u16 lK[4][64 * 64];      // [group*2 + buf] 32KB
  __shared__ u16 lP[8][16 * 64];      // 16KB (2KB/wave)
  const int hw = blockIdx.x;
  const int logical = (hw & 7) * 64 + (hw >> 3);  // 8 XCDs x 64 blocks
  const int bh = logical >> 4;            // 4 consecutive heads per XCD
  const int pair = logical & 15;
  const int b = bh >> 4, h = bh & 15;
  const int tid = threadIdx.x;
  const int w = tid >> 6, l = tid & 63;
  const int g = w >> 2, wq = w & 3;       // kv-group, q-wave within group
  const int lr = l & 15, lg = l >> 4;
  const int srow8 = l >> 3;
  const int scol = ((l & 7) ^ srow8) * 8; // pre-swizzled source col (elems)
  const u16* Kb = kb + (size_t)bh * TSEQ * 64;
  const u16* Vb = vbT + (size_t)bh * 64 * TSEQ;
  u16* lPw = lP[w];

  auto stage = [&](int buf, int kt) {     // K only
#pragma unroll
    for (int is = 0; is < 2; ++is) {
      const int chunk = wq * 2 + is;      // 0..7, 1KB each
      const int row = chunk * 8 + srow8;  // 0..63
      __builtin_amdgcn_global_load_lds(AS1C(Kb + (size_t)(kt * 64 + row) * 64 + scol),
                                       AS3((char*)lK[g * 2 + buf] + chunk * 1024), 16, 0, 0);
    }
  };

  for (int half = 0; half < 2; ++half) {
    const int qt = half ? (31 - pair) : pair;
    const int q0 = qt * 64;

    bf16x8 qf[2];
    {
      const u16* qp = qb + ((size_t)bh * TSEQ + q0 + wq * 16 + lr) * 64 + lg * 8;
      qf[0] = *(const bf16x8*)qp;
      qf[1] = *(const bf16x8*)(qp + 32);
    }

    f32x4 oacc[4] = {};
    float lsum = 0.f;

    const int nt = qt + 1;
    const int nit = (nt + 1) >> 1;
    const int ql = wq * 16 + lr;

    __syncthreads();                 // prev half's merge reads done; LDS free
    if (g < nt) stage(0, g);
    for (int it = 0; it < nit; ++it) {
      const int cur = it & 1;
      __syncthreads();               // staged buf[cur] visible to whole group
      const int ktn = 2 * (it + 1) + g;
      if (ktn < nt) stage(cur ^ 1, ktn);
      const int kt = 2 * it + g;
      if (kt < nt) {
        const u16* Kc = lK[g * 2 + cur];
        const int kv0 = kt * 64;

        // V fragments: issue DIRECT global loads first (L2 hits); the
        // QK^T MFMAs + softmax below hide the latency before first PV use.
        bf16x8 vf[4][2];
#pragma unroll
        for (int n = 0; n < 4; ++n)
#pragma unroll
          for (int ks = 0; ks < 2; ++ks)
            vf[n][ks] = *(const bf16x8*)(Vb + (size_t)(n * 16 + lr) * TSEQ + kv0 + (ks * 4 + lg) * 8);

        // S^T = K Q^T: lane holds S[q=lr][kv = n*16 + lg*4 + r] (log2 domain)
        f32x4 s[4] = {};
        __builtin_amdgcn_s_setprio(1);
#pragma unroll
        for (int n = 0; n < 4; ++n) {
          const int row = n * 16 + lr;
#pragma unroll
          for (int ks = 0; ks < 2; ++ks) {
            const int sl = (ks * 4 + lg) ^ (row & 7);
            bf16x8 kf = *(const bf16x8*)(&Kc[row * 64 + sl * 8]);
            s[n] = mfma16x16(kf, qf[ks], s[n]);
          }
        }
        __builtin_amdgcn_s_setprio(0);

        // P = exp2(s) raw; masked entries zeroed; per-lane partial sums.
        const bool diag = (kt == qt);
#pragma unroll
        for (int n = 0; n < 4; ++n) {
          float pv[4];
#pragma unroll
          for (int r = 0; r < 4; ++r) {
            float p = __builtin_amdgcn_exp2f(s[n][r]);
            if (diag && (n * 16 + lg * 4 + r > ql)) p = 0.f;
            pv[r] = p;
            lsum += p;
          }
          const u32 w0 = pack2bf(pv[0], pv[1]);
          const u32 w1 = pack2bf(pv[2], pv[3]);
          const int phys = (n * 2 + (lg >> 1)) ^ (lr & 7);
          uint2 pk; pk.x = w0; pk.y = w1;
          *(uint2*)(&lPw[lr * 64 + phys * 8 + (lg & 1) * 4]) = pk;
        }

        // O^T += V P^T: lane holds O[q=lr][d = n*16 + lg*4 + r]
        bf16x8 pf[2];
#pragma unroll
        for (int ks = 0; ks < 2; ++ks) {
          const int phys = (ks * 4 + lg) ^ (lr & 7);
          pf[ks] = *(const bf16x8*)(&lPw[lr * 64 + phys * 8]);
        }
        __builtin_amdgcn_s_setprio(1);
#pragma unroll
        for (int n = 0; n < 4; ++n)
#pragma unroll
          for (int ks = 0; ks < 2; ++ks)
            oacc[n] = mfma16x16(vf[n][ks], pf[ks], oacc[n]);
        __builtin_amdgcn_s_setprio(0);
      }
    }

    // row-total of this group's partial sums (single reduction per q-tile)
    lsum += __shfl_xor(lsum, 16);
    lsum += __shfl_xor(lsum, 32);

    // merge the two groups' (O, l) through LDS — no exp scaling needed
    __syncthreads();                  // all compute done; K LDS reusable
    float* mO = (float*)&lK[0][0];    // 4 waves x 1024 f32 = 16KB
    float* mL = (float*)&lP[0][0];    // 4 waves x 16 f32 (P no longer needed)
    if (g == 1) {
#pragma unroll
      for (int n = 0; n < 4; ++n)
#pragma unroll
        for (int r = 0; r < 4; ++r) {
          const int d = n * 16 + lg * 4 + r;
          mO[wq * 1024 + d * 16 + lr] = oacc[n][r];
        }
      if (lg == 0) mL[wq * 16 + lr] = lsum;
    }
    __syncthreads();
    if (g == 0) {
      const float rl = 1.f / (lsum + mL[wq * 16 + lr]);
      const int q = q0 + wq * 16 + lr;
#pragma unroll
      for (int n = 0; n < 4; ++n) {
        ushort4 ov;
#pragma unroll
        for (int r = 0; r < 4; ++r) {
          const int d = n * 16 + lg * 4 + r;
          const float o = oacc[n][r] + mO[wq * 1024 + d * 16 + lr];
          ((u16*)&ov)[r] = f2bf(o * rl);
        }
        *(ushort4*)(&ob[(size_t)(b * TSEQ + q) * DM + h * 64 + n * 16 + lg * 4]) = ov;
      }
    }
  }
}

// ---------------- launch ----------------
extern "C" void kernel_launch(void* const* d_in, const int* in_sizes, int n_in,
                              void* d_out, int out_size, void* d_ws, size_t ws_size,
                              hipStream_t stream) {
  const float* x    = (const float*)d_in[0];
  const float* Wqkv = (const float*)d_in[1];
  const float* Wo   = (const float*)d_in[2];
  float* out = (float*)d_out;

  char* ws = (char*)d_ws;
  u16* xb    = (u16*)ws; ws += (size_t)MROWS * DM * 2;
  u16* wqkvb = (u16*)ws; ws += (size_t)3 * DM * DM * 2;
  u16* wob   = (u16*)ws; ws += (size_t)DM * DM * 2;
  u16* qkvb  = (u16*)ws; ws += (size_t)MROWS * 3 * DM * 2;
  u16* qb    = (u16*)ws; ws += (size_t)BB * NHEADS * TSEQ * HDIM * 2;
  u16* kb    = (u16*)ws; ws += (size_t)BB * NHEADS * TSEQ * HDIM * 2;
  u16* vbT   = (u16*)ws; ws += (size_t)BB * NHEADS * TSEQ * HDIM * 2;
  u16* ob    = (u16*)ws; ws += (size_t)MROWS * DM * 2;

  cast_all<<<2048, 256, 0, stream>>>(x, Wqkv, Wo, xb, wqkvb, wob);

  gemm_bt<1><<<dim3(3 * DM / 128, MROWS / 128), 256, 0, stream>>>(
      xb, wqkvb, nullptr, qkvb, MROWS, 3 * DM, DM);

  rope_reshape<<<dim3(TSEQ / 64, BB * NHEADS), 256, 0, stream>>>(qkvb, qb, kb, vbT);

  attn_fwd<<<512, 512, 0, stream>>>(qb, kb, vbT, ob);

  gemm_bt<0><<<dim3(DM / 128, MROWS / 128), 256, 0, stream>>>(
      ob, wob, out, nullptr, MROWS, DM, DM);
}

// Round 12
// 124.322 us; speedup vs baseline: 1.1661x; 1.1661x over previous
//
#include <hip/hip_runtime.h>
#include <hip/hip_bf16.h>
#include <cstdint>

#define NHEADS 16
#define HDIM 64
#define BB 2
#define TSEQ 2048
#define DM 1024
#define MROWS (BB*TSEQ)   // 4096

typedef unsigned short u16;
typedef unsigned int u32;
typedef __bf16 bf16x8 __attribute__((ext_vector_type(8)));
typedef float f32x4 __attribute__((ext_vector_type(4)));

#define AS1C(p) ((const __attribute__((address_space(1))) u32*)(p))
#define AS3(p)  ((__attribute__((address_space(3))) u32*)(p))

static __device__ __forceinline__ u16 f2bf(float f) {
  return __builtin_bit_cast(u16, __float2bfloat16(f));
}
static __device__ __forceinline__ float bf2f(u16 u) {
  return __bfloat162float(__builtin_bit_cast(__hip_bfloat16, u));
}
// pack two non-NaN floats to bf16 pair (round-half-up, max rel err 2^-8)
static __device__ __forceinline__ u32 pack2bf(float a, float b) {
  const u32 ua = __builtin_bit_cast(u32, a) + 0x8000u;
  const u32 ub = __builtin_bit_cast(u32, b) + 0x8000u;
  return (ua >> 16) | (ub & 0xFFFF0000u);
}
static __device__ __forceinline__ f32x4 mfma16x16(bf16x8 a, bf16x8 b, f32x4 c) {
  return __builtin_amdgcn_mfma_f32_16x16x32_bf16(a, b, c, 0, 0, 0);
}

// ---------------- fused cast fp32 -> bf16 for x, W_qkv, W_o ----------------
#define N4_X   (MROWS * DM / 4)
#define N4_WQ  (3 * DM * DM / 4)
#define N4_WO  (DM * DM / 4)
__global__ __launch_bounds__(256) void cast_all(const float* __restrict__ x,
                                                const float* __restrict__ wq,
                                                const float* __restrict__ wo,
                                                u16* __restrict__ xb,
                                                u16* __restrict__ wqb,
                                                u16* __restrict__ wob) {
  int i = blockIdx.x * 256 + threadIdx.x;
  const int stride = gridDim.x * 256;
  for (; i < N4_X + N4_WQ + N4_WO; i += stride) {
    const float4* src; u16* dst; int j;
    if (i < N4_X)            { src = (const float4*)x;  dst = xb;  j = i; }
    else if (i < N4_X + N4_WQ) { src = (const float4*)wq; dst = wqb; j = i - N4_X; }
    else                     { src = (const float4*)wo; dst = wob; j = i - N4_X - N4_WQ; }
    float4 v = src[j];
    ushort4 o;
    o.x = f2bf(v.x); o.y = f2bf(v.y); o.z = f2bf(v.z); o.w = f2bf(v.w);
    ((ushort4*)dst)[j] = o;
  }
}

// ---------------- bf16 GEMM, C[m,n] = sum_k A[m,k]*B[n,k] ----------------
template<int WRITE_BF16>
__global__ __launch_bounds__(256, 2) void gemm_bt(const u16* __restrict__ A,
                                                  const u16* __restrict__ Bm,
                                                  float* __restrict__ Cf,
                                                  u16* __restrict__ Cb,
                                                  int M, int N, int K) {
  __shared__ u16 lA[2][128 * 32];
  __shared__ u16 lB[2][128 * 32];
  const int tid = threadIdx.x;
  const int w = tid >> 6, l = tid & 63;
  const int wr = w >> 1, wc = w & 1;
  int bid = blockIdx.y * gridDim.x + blockIdx.x;
  const int cpx = (gridDim.x * gridDim.y) >> 3;
  bid = (bid & 7) * cpx + (bid >> 3);
  const int bx = bid % gridDim.x, by = bid / gridDim.x;
  const int brow = by * 128, bcol = bx * 128;
  const int lr = l & 15, lg = l >> 4;

  const int srow = l >> 2;
  const int scol = (((l & 3) ^ (srow & 3)) * 8);

  auto stage = [&](int buf, int k0) {
#pragma unroll
    for (int is = 0; is < 2; ++is) {
      const int chunk = w * 2 + is;
      const int row = chunk * 16 + srow;
      __builtin_amdgcn_global_load_lds(AS1C(A + (size_t)(brow + row) * K + k0 + scol),
                                       AS3((char*)lA[buf] + chunk * 1024), 16, 0, 0);
      __builtin_amdgcn_global_load_lds(AS1C(Bm + (size_t)(bcol + row) * K + k0 + scol),
                                       AS3((char*)lB[buf] + chunk * 1024), 16, 0, 0);
    }
  };

  f32x4 acc[4][4] = {};
  const int nk = K >> 5;
  stage(0, 0);
  for (int kk = 0; kk < nk; ++kk) {
    const int cur = kk & 1;
    __syncthreads();
    if (kk + 1 < nk) stage(cur ^ 1, (kk + 1) << 5);
    bf16x8 af[4], bfr[4];
#pragma unroll
    for (int m = 0; m < 4; ++m) {
      const int row = wr * 64 + m * 16 + lr;
      const int sl = lg ^ (row & 3);
      af[m] = *(const bf16x8*)(&lA[cur][row * 32 + sl * 8]);
    }
#pragma unroll
    for (int n = 0; n < 4; ++n) {
      const int row = wc * 64 + n * 16 + lr;
      const int sl = lg ^ (row & 3);
      bfr[n] = *(const bf16x8*)(&lB[cur][row * 32 + sl * 8]);
    }
#pragma unroll
    for (int m = 0; m < 4; ++m)
#pragma unroll
      for (int n = 0; n < 4; ++n)
        acc[m][n] = mfma16x16(af[m], bfr[n], acc[m][n]);
  }
#pragma unroll
  for (int m = 0; m < 4; ++m)
#pragma unroll
    for (int n = 0; n < 4; ++n)
#pragma unroll
      for (int r = 0; r < 4; ++r) {
        const int row = brow + wr * 64 + m * 16 + lg * 4 + r;
        const int col = bcol + wc * 64 + n * 16 + lr;
        if constexpr (WRITE_BF16)
          Cb[(size_t)row * N + col] = f2bf(acc[m][n][r]);
        else
          Cf[(size_t)row * N + col] = acc[m][n][r];
      }
}

// ---------------- RoPE + reshape (vectorized, hw sin/cos) ----------------
__global__ __launch_bounds__(256) void rope_reshape(const u16* __restrict__ qkvb,
                                                    u16* __restrict__ qb,
                                                    u16* __restrict__ kb,
                                                    u16* __restrict__ vbT) {
  const int bh = blockIdx.y;
  const int b = bh >> 4, h = bh & 15;
  const int t0 = blockIdx.x * 64;
  const int tid = threadIdx.x;
  const float C = -0.4152410118609203f;  // -log2(10000)/32
  const float QS = 0.125f * 1.44269504088896341f;
  const float R2PI = 0.15915494309189535f;

  for (int idx = tid; idx < 64 * 8; idx += 256) {
    const int tl = idx >> 3, grp = idx & 7;
    const int t = t0 + tl;
    const size_t base = ((size_t)(b * TSEQ + t)) * 3072 + h * 64 + grp * 8;
    u16 qv[8], kv8[8], qo[8], ko[8];
    *(uint4*)qv  = *(const uint4*)(qkvb + base);
    *(uint4*)kv8 = *(const uint4*)(qkvb + base + 1024);
#pragma unroll
    for (int j = 0; j < 4; ++j) {
      const int p = grp * 4 + j;
      const float inv = exp2f((float)p * C);
      const float rev = __builtin_amdgcn_fractf((float)t * inv * R2PI);
      const float sn = __builtin_amdgcn_sinf(rev);
      const float cs = __builtin_amdgcn_cosf(rev);
      const float qe = bf2f(qv[2 * j]), qoo = bf2f(qv[2 * j + 1]);
      const float ke = bf2f(kv8[2 * j]), koo = bf2f(kv8[2 * j + 1]);
      qo[2 * j]     = f2bf((qe * cs - qoo * sn) * QS);
      qo[2 * j + 1] = f2bf((qe * sn + qoo * cs) * QS);
      ko[2 * j]     = f2bf(ke * cs - koo * sn);
      ko[2 * j + 1] = f2bf(ke * sn + koo * cs);
    }
    const size_t obase = ((size_t)bh * TSEQ + t) * 64 + grp * 8;
    *(uint4*)(qb + obase) = *(uint4*)qo;
    *(uint4*)(kb + obase) = *(uint4*)ko;
  }

  __shared__ u16 lT[64][65];
  for (int idx = tid; idx < 64 * 64; idx += 256) {
    const int tl = idx >> 6, d = idx & 63;
    lT[tl][d] = qkvb[((size_t)(b * TSEQ + t0 + tl)) * 3072 + 2048 + h * 64 + d];
  }
  __syncthreads();
  for (int idx = tid; idx < 64 * 64; idx += 256) {
    const int d = idx >> 6, tl = idx & 63;
    vbT[((size_t)bh * 64 + d) * TSEQ + t0 + tl] = lT[tl][d];
  }
}

// ------------- causal flash attention: kv-split quarters + merge -----------
// Each 128-row q-tile j's kv range [0, 4j+4) of 32-row tiles splits into 4
// quarters of j+1 tiles. Block = taskA (jA, qA) + taskB (15-jA, 3-qA): work
// = (jA+1)+(16-jA) = 17 tiles, exactly uniform. 1024 blocks = 32bh x 32
// slots -> 4 blocks/CU, 16 waves/CU, 21KB LDS. Each staged tile is shared
// by 128 q-rows (TA-efficient); each wave computes 32 q-rows (2 subtiles,
// DS-efficient). No-max softmax => partials merge ADDITIVELY: attn writes
// bf16 partial O + f32 partial l per quarter; attn_merge sums 4 quarters.
__global__ __launch_bounds__(256, 4) void attn_fwd(const u16* __restrict__ qb,
                                                   const u16* __restrict__ kb,
                                                   const u16* __restrict__ vbT,
                                                   u16* __restrict__ pO,
                                                   float* __restrict__ pL) {
  __shared__ u16 lK[2][32 * 64];   // 8KB (dbuf, 128B rows)
  __shared__ u16 lV[2][64 * 32];   // 8KB (dbuf, 64B rows)
  __shared__ u16 lP[4][16 * 40];   // 5KB (80B padded rows, wave-private)
  const int hw = blockIdx.x;
  const int logical = (hw & 7) * 128 + (hw >> 3);  // 8 XCDs x 128 blocks
  const int bh = logical >> 5;            // 4 consecutive heads per XCD
  const int s = logical & 31;
  const int jA = s & 15, qA = s >> 4;     // taskA quarter
  const int tid = threadIdx.x;
  const int w = tid >> 6, l = tid & 63;
  const int lr = l & 15, lg = l >> 4;
  const int kscol = ((l & 7) ^ (l >> 3)) * 8;          // K stage src swizzle
  const int vscol = ((l & 3) ^ ((l >> 3) & 3)) * 8;    // V stage src swizzle
  const u16* Kb = kb + (size_t)bh * TSEQ * 64;
  const u16* Vb = vbT + (size_t)bh * 64 * TSEQ;
  u16* lPw = lP[w];

  auto stage = [&](int buf, int kt) {      // kt = 32-row kv tile index
    const int krow = w * 8 + (l >> 3);     // wave w stages K-chunk w
    __builtin_amdgcn_global_load_lds(AS1C(Kb + (size_t)(kt * 32 + krow) * 64 + kscol),
                                     AS3((char*)lK[buf] + w * 1024), 16, 0, 0);
    const int vrow = w * 16 + (l >> 2);    // and V-chunk w (16 d-rows x 64B)
    __builtin_amdgcn_global_load_lds(AS1C(Vb + (size_t)vrow * TSEQ + kt * 32 + vscol),
                                     AS3((char*)lV[buf] + w * 1024), 16, 0, 0);
  };

  for (int task = 0; task < 2; ++task) {
    const int j  = task ? (15 - jA) : jA;
    const int qq = task ? (3 - qA) : qA;
    const int nt = j + 1;                  // tiles in this quarter
    const int kt0 = qq * nt;
    const int q0 = j * 128;
    const int ktd = 4 * j + w;             // wave's diagonal kv32 tile
    const int qa0 = q0 + w * 32 + lr;      // sub0 absolute q row

    bf16x8 qf[2][2];
    {
      const u16* qp = qb + ((size_t)bh * TSEQ + q0 + w * 32 + lr) * 64 + lg * 8;
      qf[0][0] = *(const bf16x8*)qp;
      qf[0][1] = *(const bf16x8*)(qp + 32);
      qp += 16 * 64;
      qf[1][0] = *(const bf16x8*)qp;
      qf[1][1] = *(const bf16x8*)(qp + 32);
    }

    f32x4 o0[4] = {}, o1[4] = {};
    float ls0 = 0.f, ls1 = 0.f;

    __syncthreads();                 // prev task's reads done; buffers free
    stage(0, kt0);
    for (int it = 0; it < nt; ++it) {
      const int cur = it & 1;
      __syncthreads();               // staged buf[cur] visible
      if (it + 1 < nt) stage(cur ^ 1, kt0 + it + 1);
      const int kt = kt0 + it;
      if (kt <= ktd) {
        const u16* Kc = lK[cur];
        const u16* Vc = lV[cur];

        // K fragments (shared by both q-subtiles)
        bf16x8 kf[2][2];
#pragma unroll
        for (int n = 0; n < 2; ++n) {
          const int row = n * 16 + lr;
#pragma unroll
          for (int ks = 0; ks < 2; ++ks)
            kf[n][ks] = *(const bf16x8*)(&Kc[row * 64 + (((ks * 4 + lg) ^ (row & 7)) * 8)]);
        }
        f32x4 s0[2] = {}, s1[2] = {};
        __builtin_amdgcn_s_setprio(1);
#pragma unroll
        for (int n = 0; n < 2; ++n)
#pragma unroll
          for (int ks = 0; ks < 2; ++ks) {
            s0[n] = mfma16x16(kf[n][ks], qf[0][ks], s0[n]);
            s1[n] = mfma16x16(kf[n][ks], qf[1][ks], s1[n]);
          }
        __builtin_amdgcn_s_setprio(0);

        const bool diag = (kt == ktd);
        const int kvb = kt * 32;

        // sub0: P = exp2(s), mask, pack -> padded P rows; read pf0
#pragma unroll
        for (int n = 0; n < 2; ++n) {
          float pv[4];
#pragma unroll
          for (int r = 0; r < 4; ++r) {
            float p = __builtin_amdgcn_exp2f(s0[n][r]);
            if (diag && (kvb + n * 16 + lg * 4 + r > qa0)) p = 0.f;
            pv[r] = p;
            ls0 += p;
          }
          uint2 pk; pk.x = pack2bf(pv[0], pv[1]); pk.y = pack2bf(pv[2], pv[3]);
          *(uint2*)(&lPw[lr * 40 + n * 16 + lg * 4]) = pk;
        }
        bf16x8 pf0 = *(const bf16x8*)(&lPw[lr * 40 + lg * 8]);

        // sub1: reuse the same buffer (wave-ordered DS ops)
#pragma unroll
        for (int n = 0; n < 2; ++n) {
          float pv[4];
#pragma unroll
          for (int r = 0; r < 4; ++r) {
            float p = __builtin_amdgcn_exp2f(s1[n][r]);
            if (diag && (kvb + n * 16 + lg * 4 + r > qa0 + 16)) p = 0.f;
            pv[r] = p;
            ls1 += p;
          }
          uint2 pk; pk.x = pack2bf(pv[0], pv[1]); pk.y = pack2bf(pv[2], pv[3]);
          *(uint2*)(&lPw[lr * 40 + n * 16 + lg * 4]) = pk;
        }
        bf16x8 pf1 = *(const bf16x8*)(&lPw[lr * 40 + lg * 8]);

        // O^T += V P^T, single V pass (K=32), V swizzle slot = lg^((row>>1)&3)
        __builtin_amdgcn_s_setprio(1);
#pragma unroll
        for (int n = 0; n < 4; ++n) {
          const int row = n * 16 + lr;   // d
          bf16x8 vf = *(const bf16x8*)(&Vc[row * 32 + ((lg ^ ((row >> 1) & 3)) * 8)]);
          o0[n] = mfma16x16(vf, pf0, o0[n]);
          o1[n] = mfma16x16(vf, pf1, o1[n]);
        }
        __builtin_amdgcn_s_setprio(0);
      }
    }

    // per-row partial sums (q = lr after reduce)
    ls0 += __shfl_xor(ls0, 16); ls0 += __shfl_xor(ls0, 32);
    ls1 += __shfl_xor(ls1, 16); ls1 += __shfl_xor(ls1, 32);

    // write bf16 partial O and f32 partial l for this quarter
    const size_t pbase = ((size_t)(qq * 32 + bh)) * TSEQ;
#pragma unroll
    for (int qs = 0; qs < 2; ++qs) {
      const int row = q0 + w * 32 + qs * 16 + lr;
#pragma unroll
      for (int n = 0; n < 4; ++n) {
        uint2 ov;
        if (qs == 0) { ov.x = pack2bf(o0[n][0], o0[n][1]); ov.y = pack2bf(o0[n][2], o0[n][3]); }
        else         { ov.x = pack2bf(o1[n][0], o1[n][1]); ov.y = pack2bf(o1[n][2], o1[n][3]); }
        *(uint2*)(&pO[(pbase + row) * 64 + n * 16 + lg * 4]) = ov;
      }
    }
    if (lg == 0) {
      pL[pbase + q0 + w * 32 + lr] = ls0;
      pL[pbase + q0 + w * 32 + 16 + lr] = ls1;
    }
  }
}

// merge 4 kv-quarter partials: out = (sum O_q) / (sum l_q)
__global__ __launch_bounds__(256) void attn_merge(const u16* __restrict__ pO,
                                                  const float* __restrict__ pL,
                                                  u16* __restrict__ ob) {
  const int hw = blockIdx.x;
  const int logical = (hw & 7) * 64 + (hw >> 3);  // same XCD->bh mapping
  const int bh = logical >> 4;
  const int rseg = logical & 15;
  const int b = bh >> 4, h = bh & 15;
  const int tid = threadIdx.x;
  const int row = rseg * 128 + (tid >> 1);
  const int dh = (tid & 1) * 32;

  float acc[32] = {};
  float lsum = 0.f;
#pragma unroll
  for (int q = 0; q < 4; ++q) {
    const size_t pbase = ((size_t)(q * 32 + bh)) * TSEQ + row;
    lsum += pL[pbase];
#pragma unroll
    for (int k = 0; k < 4; ++k) {
      uint4 v = *(const uint4*)(pO + pbase * 64 + dh + k * 8);
      const u16* pv = (const u16*)&v;
#pragma unroll
      for (int e = 0; e < 8; ++e) acc[k * 8 + e] += bf2f(pv[e]);
    }
  }
  const float rl = 1.f / lsum;
  u16 outv[32];
#pragma unroll
  for (int e = 0; e < 32; ++e) outv[e] = f2bf(acc[e] * rl);
  u16* dst = ob + ((size_t)(b * TSEQ) + row) * DM + h * 64 + dh;
#pragma unroll
  for (int k = 0; k < 4; ++k)
    *(uint4*)(dst + k * 8) = ((uint4*)outv)[k];
}

// ---------------- launch ----------------
extern "C" void kernel_launch(void* const* d_in, const int* in_sizes, int n_in,
                              void* d_out, int out_size, void* d_ws, size_t ws_size,
                              hipStream_t stream) {
  const float* x    = (const float*)d_in[0];
  const float* Wqkv = (const float*)d_in[1];
  const float* Wo   = (const float*)d_in[2];
  float* out = (float*)d_out;

  char* ws = (char*)d_ws;
  // region A (39.9MB): xb | wqkvb | qkvb — all dead after rope_reshape;
  // reused by attn partials (pO 33.6MB + pL 1.1MB).
  char* regA = ws;
  u16* xb    = (u16*)regA;
  u16* wqkvb = (u16*)(regA + (size_t)MROWS * DM * 2);
  u16* qkvb  = (u16*)(regA + (size_t)MROWS * DM * 2 + (size_t)3 * DM * DM * 2);
  ws += (size_t)MROWS * DM * 2 + (size_t)3 * DM * DM * 2 + (size_t)MROWS * 3 * DM * 2;
  u16* pO = (u16*)regA;                                   // 4*32*2048*64*2B
  float* pL = (float*)(regA + (size_t)4 * 32 * TSEQ * 64 * 2);

  u16* wob = (u16*)ws; ws += (size_t)DM * DM * 2;
  u16* qb  = (u16*)ws; ws += (size_t)BB * NHEADS * TSEQ * HDIM * 2;
  u16* kb  = (u16*)ws; ws += (size_t)BB * NHEADS * TSEQ * HDIM * 2;
  u16* vbT = (u16*)ws; ws += (size_t)BB * NHEADS * TSEQ * HDIM * 2;
  u16* ob  = (u16*)ws; ws += (size_t)MROWS * DM * 2;

  cast_all<<<2048, 256, 0, stream>>>(x, Wqkv, Wo, xb, wqkvb, wob);

  gemm_bt<1><<<dim3(3 * DM / 128, MROWS / 128), 256, 0, stream>>>(
      xb, wqkvb, nullptr, qkvb, MROWS, 3 * DM, DM);

  rope_reshape<<<dim3(TSEQ / 64, BB * NHEADS), 256, 0, stream>>>(qkvb, qb, kb, vbT);

  attn_fwd<<<1024, 256, 0, stream>>>(qb, kb, vbT, pO, pL);

  attn_merge<<<512, 256, 0, stream>>>(pO, pL, ob);

  gemm_bt<0><<<dim3(DM / 128, MROWS / 128), 256, 0, stream>>>(
      ob, wob, out, nullptr, MROWS, DM, DM);
}

// Round 13
// 106.667 us; speedup vs baseline: 1.3591x; 1.1655x over previous
//
#include <hip/hip_runtime.h>
#include <hip/hip_bf16.h>
#include <cstdint>

#define NHEADS 16
#define HDIM 64
#define BB 2
#define TSEQ 2048
#define DM 1024
#define MROWS (BB*TSEQ)   // 4096

typedef unsigned short u16;
typedef unsigned int u32;
typedef __bf16 bf16x8 __attribute__((ext_vector_type(8)));
typedef float f32x4 __attribute__((ext_vector_type(4)));

#define AS1C(p) ((const __attribute__((address_space(1))) u32*)(p))
#define AS3(p)  ((__attribute__((address_space(3))) u32*)(p))

static __device__ __forceinline__ u16 f2bf(float f) {
  return __builtin_bit_cast(u16, __float2bfloat16(f));
}
static __device__ __forceinline__ float bf2f(u16 u) {
  return __bfloat162float(__builtin_bit_cast(__hip_bfloat16, u));
}
// pack two non-NaN floats to bf16 pair (round-half-up, max rel err 2^-8)
static __device__ __forceinline__ u32 pack2bf(float a, float b) {
  const u32 ua = __builtin_bit_cast(u32, a) + 0x8000u;
  const u32 ub = __builtin_bit_cast(u32, b) + 0x8000u;
  return (ua >> 16) | (ub & 0xFFFF0000u);
}
static __device__ __forceinline__ f32x4 mfma16x16(bf16x8 a, bf16x8 b, f32x4 c) {
  return __builtin_amdgcn_mfma_f32_16x16x32_bf16(a, b, c, 0, 0, 0);
}

// ---------------- fused cast fp32 -> bf16 for x, W_qkv, W_o ----------------
#define N4_X   (MROWS * DM / 4)
#define N4_WQ  (3 * DM * DM / 4)
#define N4_WO  (DM * DM / 4)
__global__ __launch_bounds__(256) void cast_all(const float* __restrict__ x,
                                                const float* __restrict__ wq,
                                                const float* __restrict__ wo,
                                                u16* __restrict__ xb,
                                                u16* __restrict__ wqb,
                                                u16* __restrict__ wob) {
  int i = blockIdx.x * 256 + threadIdx.x;
  const int stride = gridDim.x * 256;
  for (; i < N4_X + N4_WQ + N4_WO; i += stride) {
    const float4* src; u16* dst; int j;
    if (i < N4_X)            { src = (const float4*)x;  dst = xb;  j = i; }
    else if (i < N4_X + N4_WQ) { src = (const float4*)wq; dst = wqb; j = i - N4_X; }
    else                     { src = (const float4*)wo; dst = wob; j = i - N4_X - N4_WQ; }
    float4 v = src[j];
    ushort4 o;
    o.x = f2bf(v.x); o.y = f2bf(v.y); o.z = f2bf(v.z); o.w = f2bf(v.w);
    ((ushort4*)dst)[j] = o;
  }
}

// ---------------- bf16 GEMM 128x128, C[m,n] = sum_k A[m,k]*B[n,k] ----------
template<int WRITE_BF16>
__global__ __launch_bounds__(256, 2) void gemm_bt(const u16* __restrict__ A,
                                                  const u16* __restrict__ Bm,
                                                  float* __restrict__ Cf,
                                                  u16* __restrict__ Cb,
                                                  int M, int N, int K) {
  __shared__ u16 lA[2][128 * 32];
  __shared__ u16 lB[2][128 * 32];
  const int tid = threadIdx.x;
  const int w = tid >> 6, l = tid & 63;
  const int wr = w >> 1, wc = w & 1;
  int bid = blockIdx.y * gridDim.x + blockIdx.x;
  const int cpx = (gridDim.x * gridDim.y) >> 3;
  bid = (bid & 7) * cpx + (bid >> 3);
  const int bx = bid % gridDim.x, by = bid / gridDim.x;
  const int brow = by * 128, bcol = bx * 128;
  const int lr = l & 15, lg = l >> 4;

  const int srow = l >> 2;
  const int scol = (((l & 3) ^ (srow & 3)) * 8);

  auto stage = [&](int buf, int k0) {
#pragma unroll
    for (int is = 0; is < 2; ++is) {
      const int chunk = w * 2 + is;
      const int row = chunk * 16 + srow;
      __builtin_amdgcn_global_load_lds(AS1C(A + (size_t)(brow + row) * K + k0 + scol),
                                       AS3((char*)lA[buf] + chunk * 1024), 16, 0, 0);
      __builtin_amdgcn_global_load_lds(AS1C(Bm + (size_t)(bcol + row) * K + k0 + scol),
                                       AS3((char*)lB[buf] + chunk * 1024), 16, 0, 0);
    }
  };

  f32x4 acc[4][4] = {};
  const int nk = K >> 5;
  stage(0, 0);
  for (int kk = 0; kk < nk; ++kk) {
    const int cur = kk & 1;
    __syncthreads();
    if (kk + 1 < nk) stage(cur ^ 1, (kk + 1) << 5);
    bf16x8 af[4], bfr[4];
#pragma unroll
    for (int m = 0; m < 4; ++m) {
      const int row = wr * 64 + m * 16 + lr;
      const int sl = lg ^ (row & 3);
      af[m] = *(const bf16x8*)(&lA[cur][row * 32 + sl * 8]);
    }
#pragma unroll
    for (int n = 0; n < 4; ++n) {
      const int row = wc * 64 + n * 16 + lr;
      const int sl = lg ^ (row & 3);
      bfr[n] = *(const bf16x8*)(&lB[cur][row * 32 + sl * 8]);
    }
#pragma unroll
    for (int m = 0; m < 4; ++m)
#pragma unroll
      for (int n = 0; n < 4; ++n)
        acc[m][n] = mfma16x16(af[m], bfr[n], acc[m][n]);
  }
#pragma unroll
  for (int m = 0; m < 4; ++m)
#pragma unroll
    for (int n = 0; n < 4; ++n)
#pragma unroll
      for (int r = 0; r < 4; ++r) {
        const int row = brow + wr * 64 + m * 16 + lg * 4 + r;
        const int col = bcol + wc * 64 + n * 16 + lr;
        if constexpr (WRITE_BF16)
          Cb[(size_t)row * N + col] = f2bf(acc[m][n][r]);
        else
          Cf[(size_t)row * N + col] = acc[m][n][r];
      }
}

// ------------- bf16 GEMM 64x128 tile (fp32 out) — for M-heavy, small N -----
// Same proven 2-phase structure; grid (N/128, M/64) so gemm2 gets 512 blocks
// = 2 blocks/CU (the 128x128 grid gave only 1/CU -> no barrier hiding).
__global__ __launch_bounds__(256, 2) void gemm_bt64(const u16* __restrict__ A,
                                                    const u16* __restrict__ Bm,
                                                    float* __restrict__ Cf,
                                                    int M, int N, int K) {
  __shared__ u16 lA[2][64 * 32];
  __shared__ u16 lB[2][128 * 32];
  const int tid = threadIdx.x;
  const int w = tid >> 6, l = tid & 63;
  const int wr = w >> 1, wc = w & 1;   // waves 2x2: wave = 32 rows x 64 cols
  int bid = blockIdx.y * gridDim.x + blockIdx.x;
  const int cpx = (gridDim.x * gridDim.y) >> 3;
  bid = (bid & 7) * cpx + (bid >> 3);
  const int bx = bid % gridDim.x, by = bid / gridDim.x;
  const int brow = by * 64, bcol = bx * 128;
  const int lr = l & 15, lg = l >> 4;

  const int srow = l >> 2;
  const int scol = (((l & 3) ^ (srow & 3)) * 8);

  auto stage = [&](int buf, int k0) {
    // A: 64 rows = 4 chunks, one per wave
    {
      const int row = w * 16 + srow;
      __builtin_amdgcn_global_load_lds(AS1C(A + (size_t)(brow + row) * K + k0 + scol),
                                       AS3((char*)lA[buf] + w * 1024), 16, 0, 0);
    }
    // B: 128 rows = 8 chunks, two per wave
#pragma unroll
    for (int is = 0; is < 2; ++is) {
      const int chunk = w * 2 + is;
      const int row = chunk * 16 + srow;
      __builtin_amdgcn_global_load_lds(AS1C(Bm + (size_t)(bcol + row) * K + k0 + scol),
                                       AS3((char*)lB[buf] + chunk * 1024), 16, 0, 0);
    }
  };

  f32x4 acc[2][4] = {};
  const int nk = K >> 5;
  stage(0, 0);
  for (int kk = 0; kk < nk; ++kk) {
    const int cur = kk & 1;
    __syncthreads();
    if (kk + 1 < nk) stage(cur ^ 1, (kk + 1) << 5);
    bf16x8 af[2], bfr[4];
#pragma unroll
    for (int m = 0; m < 2; ++m) {
      const int row = wr * 32 + m * 16 + lr;
      const int sl = lg ^ (row & 3);
      af[m] = *(const bf16x8*)(&lA[cur][row * 32 + sl * 8]);
    }
#pragma unroll
    for (int n = 0; n < 4; ++n) {
      const int row = wc * 64 + n * 16 + lr;
      const int sl = lg ^ (row & 3);
      bfr[n] = *(const bf16x8*)(&lB[cur][row * 32 + sl * 8]);
    }
#pragma unroll
    for (int m = 0; m < 2; ++m)
#pragma unroll
      for (int n = 0; n < 4; ++n)
        acc[m][n] = mfma16x16(af[m], bfr[n], acc[m][n]);
  }
#pragma unroll
  for (int m = 0; m < 2; ++m)
#pragma unroll
    for (int n = 0; n < 4; ++n)
#pragma unroll
      for (int r = 0; r < 4; ++r) {
        const int row = brow + wr * 32 + m * 16 + lg * 4 + r;
        const int col = bcol + wc * 64 + n * 16 + lr;
        Cf[(size_t)row * N + col] = acc[m][n][r];
      }
}

// ---------------- RoPE + reshape (vectorized, hw sin/cos) ----------------
// q pre-scaled by (1/8)*log2(e) so attention scores arrive in the log2
// domain and the softmax exp becomes a raw v_exp_f32.
__global__ __launch_bounds__(256) void rope_reshape(const u16* __restrict__ qkvb,
                                                    u16* __restrict__ qb,
                                                    u16* __restrict__ kb,
                                                    u16* __restrict__ vbT) {
  const int bh = blockIdx.y;
  const int b = bh >> 4, h = bh & 15;
  const int t0 = blockIdx.x * 64;
  const int tid = threadIdx.x;
  const float C = -0.4152410118609203f;  // -log2(10000)/32
  const float QS = 0.125f * 1.44269504088896341f;
  const float R2PI = 0.15915494309189535f;

  for (int idx = tid; idx < 64 * 8; idx += 256) {
    const int tl = idx >> 3, grp = idx & 7;
    const int t = t0 + tl;
    const size_t base = ((size_t)(b * TSEQ + t)) * 3072 + h * 64 + grp * 8;
    u16 qv[8], kv8[8], qo[8], ko[8];
    *(uint4*)qv  = *(const uint4*)(qkvb + base);
    *(uint4*)kv8 = *(const uint4*)(qkvb + base + 1024);
#pragma unroll
    for (int j = 0; j < 4; ++j) {
      const int p = grp * 4 + j;
      const float inv = exp2f((float)p * C);
      const float rev = __builtin_amdgcn_fractf((float)t * inv * R2PI);
      const float sn = __builtin_amdgcn_sinf(rev);
      const float cs = __builtin_amdgcn_cosf(rev);
      const float qe = bf2f(qv[2 * j]), qoo = bf2f(qv[2 * j + 1]);
      const float ke = bf2f(kv8[2 * j]), koo = bf2f(kv8[2 * j + 1]);
      qo[2 * j]     = f2bf((qe * cs - qoo * sn) * QS);
      qo[2 * j + 1] = f2bf((qe * sn + qoo * cs) * QS);
      ko[2 * j]     = f2bf(ke * cs - koo * sn);
      ko[2 * j + 1] = f2bf(ke * sn + koo * cs);
    }
    const size_t obase = ((size_t)bh * TSEQ + t) * 64 + grp * 8;
    *(uint4*)(qb + obase) = *(uint4*)qo;
    *(uint4*)(kb + obase) = *(uint4*)ko;
  }

  __shared__ u16 lT[64][65];
  for (int idx = tid; idx < 64 * 64; idx += 256) {
    const int tl = idx >> 6, d = idx & 63;
    lT[tl][d] = qkvb[((size_t)(b * TSEQ + t0 + tl)) * 3072 + 2048 + h * 64 + d];
  }
  __syncthreads();
  for (int idx = tid; idx < 64 * 64; idx += 256) {
    const int d = idx >> 6, tl = idx & 63;
    vbT[((size_t)bh * 64 + d) * TSEQ + t0 + tl] = lT[tl][d];
  }
}

// ---------------- causal flash attention (R5-proven configuration) --------
// 512 blocks x 512 thr (8 waves = 4 q-waves x 2 kv-groups), 2 blocks/CU;
// q-tile pair {pair, 31-pair} -> exactly 33 kv-tiles/block (uniform);
// K/V 64-row tiles double-buffered per group; no-max softmax (P=exp2(s),
// per-lane partial sums, single reduction per q-tile); XCD swizzle.
__global__ __launch_bounds__(512, 4) void attn_fwd(const u16* __restrict__ qb,
                                                   const u16* __restrict__ kb,
                                                   const u16* __restrict__ vbT,
                                                   u16* __restrict__ ob) {
  __shared__ u16 lK[4][64 * 64];
  __shared__ u16 lV[4][64 * 64];
  __shared__ u16 lP[8][16 * 64];
  const int hw = blockIdx.x;
  const int logical = (hw & 7) * 64 + (hw >> 3);  // 8 XCDs x 64 blocks
  const int bh = logical >> 4;            // 4 consecutive heads per XCD
  const int pair = logical & 15;
  const int b = bh >> 4, h = bh & 15;
  const int tid = threadIdx.x;
  const int w = tid >> 6, l = tid & 63;
  const int g = w >> 2, wq = w & 3;       // kv-group, q-wave within group
  const int lr = l & 15, lg = l >> 4;
  const int srow8 = l >> 3;
  const int scol = ((l & 7) ^ srow8) * 8; // pre-swizzled source col (elems)
  const u16* Kb = kb + (size_t)bh * TSEQ * 64;
  const u16* Vb = vbT + (size_t)bh * 64 * TSEQ;
  u16* lPw = lP[w];

  auto stage = [&](int buf, int kt) {
#pragma unroll
    for (int is = 0; is < 2; ++is) {
      const int chunk = wq * 2 + is;            // 0..7, 1KB each
      const int row = chunk * 8 + srow8;        // 0..63
      __builtin_amdgcn_global_load_lds(AS1C(Kb + (size_t)(kt * 64 + row) * 64 + scol),
                                       AS3((char*)lK[buf] + chunk * 1024), 16, 0, 0);
      __builtin_amdgcn_global_load_lds(AS1C(Vb + (size_t)row * TSEQ + kt * 64 + scol),
                                       AS3((char*)lV[buf] + chunk * 1024), 16, 0, 0);
    }
  };

  for (int half = 0; half < 2; ++half) {
    const int qt = half ? (TSEQ / 64 - 1 - pair) : pair;
    const int q0 = qt * 64;

    bf16x8 qf[2];
    {
      const u16* qp = qb + ((size_t)bh * TSEQ + q0 + wq * 16 + lr) * 64 + lg * 8;
      qf[0] = *(const bf16x8*)qp;
      qf[1] = *(const bf16x8*)(qp + 32);
    }

    f32x4 oacc[4] = {};
    float lsum = 0.f;

    const int nt = qt + 1;
    const int nit = (nt + 1) >> 1;
    const int ql = wq * 16 + lr;

    __syncthreads();                 // LDS safe to overwrite (prev half done)
    if (g < nt) stage(g * 2, g);
    for (int it = 0; it < nit; ++it) {
      const int cur = it & 1;
      __syncthreads();               // staged buf[cur] visible to whole group
      const int ktn = 2 * (it + 1) + g;
      if (ktn < nt) stage(g * 2 + (cur ^ 1), ktn);
      const int kt = 2 * it + g;
      if (kt < nt) {
        const u16* Kc = lK[g * 2 + cur];
        const u16* Vc = lV[g * 2 + cur];

        // S^T = K Q^T: lane holds S[q=lr][kv = n*16 + lg*4 + r] (log2 domain)
        f32x4 s[4] = {};
        __builtin_amdgcn_s_setprio(1);
#pragma unroll
        for (int n = 0; n < 4; ++n) {
          const int row = n * 16 + lr;
#pragma unroll
          for (int ks = 0; ks < 2; ++ks) {
            const int sl = (ks * 4 + lg) ^ (row & 7);
            bf16x8 kf = *(const bf16x8*)(&Kc[row * 64 + sl * 8]);
            s[n] = mfma16x16(kf, qf[ks], s[n]);
          }
        }
        __builtin_amdgcn_s_setprio(0);

        // P = exp2(s) raw; masked entries zeroed; per-lane partial sums.
        const bool diag = (kt == qt);
#pragma unroll
        for (int n = 0; n < 4; ++n) {
          float pv[4];
#pragma unroll
          for (int r = 0; r < 4; ++r) {
            float p = __builtin_amdgcn_exp2f(s[n][r]);
            if (diag && (n * 16 + lg * 4 + r > ql)) p = 0.f;
            pv[r] = p;
            lsum += p;
          }
          const u32 w0 = pack2bf(pv[0], pv[1]);
          const u32 w1 = pack2bf(pv[2], pv[3]);
          const int phys = (n * 2 + (lg >> 1)) ^ (lr & 7);
          uint2 pk; pk.x = w0; pk.y = w1;
          *(uint2*)(&lPw[lr * 64 + phys * 8 + (lg & 1) * 4]) = pk;
        }

        // O^T += V P^T: lane holds O[q=lr][d = n*16 + lg*4 + r]
        bf16x8 pf[2];
#pragma unroll
        for (int ks = 0; ks < 2; ++ks) {
          const int phys = (ks * 4 + lg) ^ (lr & 7);
          pf[ks] = *(const bf16x8*)(&lPw[lr * 64 + phys * 8]);
        }
        __builtin_amdgcn_s_setprio(1);
#pragma unroll
        for (int n = 0; n < 4; ++n) {
          const int row = n * 16 + lr;
#pragma unroll
          for (int ks = 0; ks < 2; ++ks) {
            const int sl = (ks * 4 + lg) ^ (row & 7);
            bf16x8 vf = *(const bf16x8*)(&Vc[row * 64 + sl * 8]);
            oacc[n] = mfma16x16(vf, pf[ks], oacc[n]);
          }
        }
        __builtin_amdgcn_s_setprio(0);
      }
    }

    // row-total of this group's partial sums (single reduction per q-tile)
    lsum += __shfl_xor(lsum, 16);
    lsum += __shfl_xor(lsum, 32);

    // merge the two groups' (O, l) through LDS — no exp scaling needed
    __syncthreads();                  // all compute done; K/V LDS reusable
    float* mO = (float*)&lK[0][0];    // 4 waves x 1024 f32 = 16KB
    float* mL = (float*)&lV[0][0];    // 4 waves x 16 f32
    if (g == 1) {
#pragma unroll
      for (int n = 0; n < 4; ++n)
#pragma unroll
        for (int r = 0; r < 4; ++r) {
          const int d = n * 16 + lg * 4 + r;
          mO[wq * 1024 + d * 16 + lr] = oacc[n][r];
        }
      if (lg == 0) mL[wq * 16 + lr] = lsum;
    }
    __syncthreads();
    if (g == 0) {
      const float rl = 1.f / (lsum + mL[wq * 16 + lr]);
      const int q = q0 + wq * 16 + lr;
#pragma unroll
      for (int n = 0; n < 4; ++n) {
        ushort4 ov;
#pragma unroll
        for (int r = 0; r < 4; ++r) {
          const int d = n * 16 + lg * 4 + r;
          const float o = oacc[n][r] + mO[wq * 1024 + d * 16 + lr];
          ((u16*)&ov)[r] = f2bf(o * rl);
        }
        *(ushort4*)(&ob[(size_t)(b * TSEQ + q) * DM + h * 64 + n * 16 + lg * 4]) = ov;
      }
    }
  }
}

// ---------------- launch ----------------
extern "C" void kernel_launch(void* const* d_in, const int* in_sizes, int n_in,
                              void* d_out, int out_size, void* d_ws, size_t ws_size,
                              hipStream_t stream) {
  const float* x    = (const float*)d_in[0];
  const float* Wqkv = (const float*)d_in[1];
  const float* Wo   = (const float*)d_in[2];
  float* out = (float*)d_out;

  char* ws = (char*)d_ws;
  u16* xb    = (u16*)ws; ws += (size_t)MROWS * DM * 2;
  u16* wqkvb = (u16*)ws; ws += (size_t)3 * DM * DM * 2;
  u16* wob   = (u16*)ws; ws += (size_t)DM * DM * 2;
  u16* qkvb  = (u16*)ws; ws += (size_t)MROWS * 3 * DM * 2;
  u16* qb    = (u16*)ws; ws += (size_t)BB * NHEADS * TSEQ * HDIM * 2;
  u16* kb    = (u16*)ws; ws += (size_t)BB * NHEADS * TSEQ * HDIM * 2;
  u16* vbT   = (u16*)ws; ws += (size_t)BB * NHEADS * TSEQ * HDIM * 2;
  u16* ob    = (u16*)ws; ws += (size_t)MROWS * DM * 2;

  cast_all<<<2048, 256, 0, stream>>>(x, Wqkv, Wo, xb, wqkvb, wob);

  gemm_bt<1><<<dim3(3 * DM / 128, MROWS / 128), 256, 0, stream>>>(
      xb, wqkvb, nullptr, qkvb, MROWS, 3 * DM, DM);

  rope_reshape<<<dim3(TSEQ / 64, BB * NHEADS), 256, 0, stream>>>(qkvb, qb, kb, vbT);

  attn_fwd<<<512, 512, 0, stream>>>(qb, kb, vbT, ob);

  gemm_bt64<<<dim3(DM / 128, MROWS / 64), 256, 0, stream>>>(
      ob, wob, out, MROWS, DM, DM);
}

// Round 14
// 100.551 us; speedup vs baseline: 1.4418x; 1.0608x over previous
//
#include <hip/hip_runtime.h>
#include <hip/hip_bf16.h>
#include <cstdint>

#define NHEADS 16
#define HDIM 64
#define BB 2
#define TSEQ 2048
#define DM 1024
#define MROWS (BB*TSEQ)   // 4096

typedef unsigned short u16;
typedef unsigned int u32;
typedef __bf16 bf16x8 __attribute__((ext_vector_type(8)));
typedef float f32x4 __attribute__((ext_vector_type(4)));

#define AS1C(p) ((const __attribute__((address_space(1))) u32*)(p))
#define AS3(p)  ((__attribute__((address_space(3))) u32*)(p))

static __device__ __forceinline__ u16 f2bf(float f) {
  return __builtin_bit_cast(u16, __float2bfloat16(f));
}
static __device__ __forceinline__ float bf2f(u16 u) {
  return __bfloat162float(__builtin_bit_cast(__hip_bfloat16, u));
}
// pack two non-NaN floats to bf16 pair (round-half-up, max rel err 2^-8)
static __device__ __forceinline__ u32 pack2bf(float a, float b) {
  const u32 ua = __builtin_bit_cast(u32, a) + 0x8000u;
  const u32 ub = __builtin_bit_cast(u32, b) + 0x8000u;
  return (ua >> 16) | (ub & 0xFFFF0000u);
}
static __device__ __forceinline__ f32x4 mfma16x16(bf16x8 a, bf16x8 b, f32x4 c) {
  return __builtin_amdgcn_mfma_f32_16x16x32_bf16(a, b, c, 0, 0, 0);
}

// ---------------- fused cast fp32 -> bf16 for x, W_qkv, W_o ----------------
#define N4_X   (MROWS * DM / 4)
#define N4_WQ  (3 * DM * DM / 4)
#define N4_WO  (DM * DM / 4)
__global__ __launch_bounds__(256) void cast_all(const float* __restrict__ x,
                                                const float* __restrict__ wq,
                                                const float* __restrict__ wo,
                                                u16* __restrict__ xb,
                                                u16* __restrict__ wqb,
                                                u16* __restrict__ wob) {
  int i = blockIdx.x * 256 + threadIdx.x;
  const int stride = gridDim.x * 256;
  for (; i < N4_X + N4_WQ + N4_WO; i += stride) {
    const float4* src; u16* dst; int j;
    if (i < N4_X)            { src = (const float4*)x;  dst = xb;  j = i; }
    else if (i < N4_X + N4_WQ) { src = (const float4*)wq; dst = wqb; j = i - N4_X; }
    else                     { src = (const float4*)wo; dst = wob; j = i - N4_X - N4_WQ; }
    float4 v = src[j];
    ushort4 o;
    o.x = f2bf(v.x); o.y = f2bf(v.y); o.z = f2bf(v.z); o.w = f2bf(v.w);
    ((ushort4*)dst)[j] = o;
  }
}

// ------- GEMM1 fused: qkv = x @ Wqkv^T, epilogue does RoPE + reshape -------
// 128x128 tile, 2-phase double-buffer (proven). Block cols never straddle the
// q/k/v boundaries (all multiples of 128). Epilogue:
//  q/k blocks: RoPE via __shfl_xor(acc,1) pair exchange + hw sin/cos; q
//    pre-scaled by (1/8)*log2(e); write [bh][t][64].
//  v blocks: direct transposed write to vbT[bh][64][TSEQ] (r=0..3 -> 8B pack).
__global__ __launch_bounds__(256, 2) void gemm_qkv(const u16* __restrict__ A,
                                                   const u16* __restrict__ Bm,
                                                   u16* __restrict__ qb,
                                                   u16* __restrict__ kbuf,
                                                   u16* __restrict__ vbT,
                                                   int M, int N, int K) {
  __shared__ u16 lA[2][128 * 32];
  __shared__ u16 lB[2][128 * 32];
  const int tid = threadIdx.x;
  const int w = tid >> 6, l = tid & 63;
  const int wr = w >> 1, wc = w & 1;
  int bid = blockIdx.y * gridDim.x + blockIdx.x;
  const int cpx = (gridDim.x * gridDim.y) >> 3;
  bid = (bid & 7) * cpx + (bid >> 3);
  const int bx = bid % gridDim.x, by = bid / gridDim.x;
  const int brow = by * 128, bcol = bx * 128;
  const int lr = l & 15, lg = l >> 4;

  const int srow = l >> 2;
  const int scol = (((l & 3) ^ (srow & 3)) * 8);

  auto stage = [&](int buf, int k0) {
#pragma unroll
    for (int is = 0; is < 2; ++is) {
      const int chunk = w * 2 + is;
      const int row = chunk * 16 + srow;
      __builtin_amdgcn_global_load_lds(AS1C(A + (size_t)(brow + row) * K + k0 + scol),
                                       AS3((char*)lA[buf] + chunk * 1024), 16, 0, 0);
      __builtin_amdgcn_global_load_lds(AS1C(Bm + (size_t)(bcol + row) * K + k0 + scol),
                                       AS3((char*)lB[buf] + chunk * 1024), 16, 0, 0);
    }
  };

  f32x4 acc[4][4] = {};
  const int nk = K >> 5;
  stage(0, 0);
  for (int kk = 0; kk < nk; ++kk) {
    const int cur = kk & 1;
    __syncthreads();
    if (kk + 1 < nk) stage(cur ^ 1, (kk + 1) << 5);
    bf16x8 af[4], bfr[4];
#pragma unroll
    for (int m = 0; m < 4; ++m) {
      const int row = wr * 64 + m * 16 + lr;
      const int sl = lg ^ (row & 3);
      af[m] = *(const bf16x8*)(&lA[cur][row * 32 + sl * 8]);
    }
#pragma unroll
    for (int n = 0; n < 4; ++n) {
      const int row = wc * 64 + n * 16 + lr;
      const int sl = lg ^ (row & 3);
      bfr[n] = *(const bf16x8*)(&lB[cur][row * 32 + sl * 8]);
    }
#pragma unroll
    for (int m = 0; m < 4; ++m)
#pragma unroll
      for (int n = 0; n < 4; ++n)
        acc[m][n] = mfma16x16(af[m], bfr[n], acc[m][n]);
  }

  const float C = -0.4152410118609203f;   // -log2(10000)/32
  const float QS = 0.125f * 1.44269504088896341f;
  const float R2PI = 0.15915494309189535f;

  if (bcol < 2048) {   // q or k block: RoPE + [bh][t][64] write
    const bool isq = (bcol < 1024);
    const int head = ((bcol + wc * 64) >> 6) & 15;
    u16* dst = isq ? qb : kbuf;
#pragma unroll
    for (int n = 0; n < 4; ++n) {
      const int d = n * 16 + lr;
      const float inv = exp2f((float)(d >> 1) * C);
#pragma unroll
      for (int m = 0; m < 4; ++m)
#pragma unroll
        for (int r = 0; r < 4; ++r) {
          const int row = brow + wr * 64 + m * 16 + lg * 4 + r;
          const int t = row & (TSEQ - 1), b = row >> 11;
          const float own = acc[m][n][r];
          const float oth = __shfl_xor(own, 1);
          const float rev = __builtin_amdgcn_fractf((float)t * inv * R2PI);
          float sn = __builtin_amdgcn_sinf(rev);
          float cs = __builtin_amdgcn_cosf(rev);
          if (isq) { sn *= QS; cs *= QS; }
          const float out = (lr & 1) ? (oth * sn + own * cs)
                                     : (own * cs - oth * sn);
          dst[(((size_t)(b * 16 + head)) * TSEQ + t) * 64 + d] = f2bf(out);
        }
    }
  } else {             // v block: transposed write to vbT[bh][64][TSEQ]
    const int head = (((bcol - 2048) + wc * 64) >> 6) & 15;
#pragma unroll
    for (int n = 0; n < 4; ++n) {
      const int d = n * 16 + lr;
#pragma unroll
      for (int m = 0; m < 4; ++m) {
        const int row0 = brow + wr * 64 + m * 16 + lg * 4;
        const int t = row0 & (TSEQ - 1), b = row0 >> 11;
        uint2 pk;
        pk.x = pack2bf(acc[m][n][0], acc[m][n][1]);
        pk.y = pack2bf(acc[m][n][2], acc[m][n][3]);
        *(uint2*)(&vbT[((size_t)(b * 16 + head) * 64 + d) * TSEQ + t]) = pk;
      }
    }
  }
}

// ------------- bf16 GEMM 64x128 tile (fp32 out) — output projection --------
__global__ __launch_bounds__(256, 2) void gemm_bt64(const u16* __restrict__ A,
                                                    const u16* __restrict__ Bm,
                                                    float* __restrict__ Cf,
                                                    int M, int N, int K) {
  __shared__ u16 lA[2][64 * 32];
  __shared__ u16 lB[2][128 * 32];
  const int tid = threadIdx.x;
  const int w = tid >> 6, l = tid & 63;
  const int wr = w >> 1, wc = w & 1;
  int bid = blockIdx.y * gridDim.x + blockIdx.x;
  const int cpx = (gridDim.x * gridDim.y) >> 3;
  bid = (bid & 7) * cpx + (bid >> 3);
  const int bx = bid % gridDim.x, by = bid / gridDim.x;
  const int brow = by * 64, bcol = bx * 128;
  const int lr = l & 15, lg = l >> 4;

  const int srow = l >> 2;
  const int scol = (((l & 3) ^ (srow & 3)) * 8);

  auto stage = [&](int buf, int k0) {
    {
      const int row = w * 16 + srow;
      __builtin_amdgcn_global_load_lds(AS1C(A + (size_t)(brow + row) * K + k0 + scol),
                                       AS3((char*)lA[buf] + w * 1024), 16, 0, 0);
    }
#pragma unroll
    for (int is = 0; is < 2; ++is) {
      const int chunk = w * 2 + is;
      const int row = chunk * 16 + srow;
      __builtin_amdgcn_global_load_lds(AS1C(Bm + (size_t)(bcol + row) * K + k0 + scol),
                                       AS3((char*)lB[buf] + chunk * 1024), 16, 0, 0);
    }
  };

  f32x4 acc[2][4] = {};
  const int nk = K >> 5;
  stage(0, 0);
  for (int kk = 0; kk < nk; ++kk) {
    const int cur = kk & 1;
    __syncthreads();
    if (kk + 1 < nk) stage(cur ^ 1, (kk + 1) << 5);
    bf16x8 af[2], bfr[4];
#pragma unroll
    for (int m = 0; m < 2; ++m) {
      const int row = wr * 32 + m * 16 + lr;
      const int sl = lg ^ (row & 3);
      af[m] = *(const bf16x8*)(&lA[cur][row * 32 + sl * 8]);
    }
#pragma unroll
    for (int n = 0; n < 4; ++n) {
      const int row = wc * 64 + n * 16 + lr;
      const int sl = lg ^ (row & 3);
      bfr[n] = *(const bf16x8*)(&lB[cur][row * 32 + sl * 8]);
    }
#pragma unroll
    for (int m = 0; m < 2; ++m)
#pragma unroll
      for (int n = 0; n < 4; ++n)
        acc[m][n] = mfma16x16(af[m], bfr[n], acc[m][n]);
  }
#pragma unroll
  for (int m = 0; m < 2; ++m)
#pragma unroll
    for (int n = 0; n < 4; ++n)
#pragma unroll
      for (int r = 0; r < 4; ++r) {
        const int row = brow + wr * 32 + m * 16 + lg * 4 + r;
        const int col = bcol + wc * 64 + n * 16 + lr;
        Cf[(size_t)row * N + col] = acc[m][n][r];
      }
}

// ---------------- causal flash attention (R5-proven configuration) --------
__global__ __launch_bounds__(512, 4) void attn_fwd(const u16* __restrict__ qb,
                                                   const u16* __restrict__ kb,
                                                   const u16* __restrict__ vbT,
                                                   u16* __restrict__ ob) {
  __shared__ u16 lK[4][64 * 64];
  __shared__ u16 lV[4][64 * 64];
  __shared__ u16 lP[8][16 * 64];
  const int hw = blockIdx.x;
  const int logical = (hw & 7) * 64 + (hw >> 3);  // 8 XCDs x 64 blocks
  const int bh = logical >> 4;            // 4 consecutive heads per XCD
  const int pair = logical & 15;
  const int b = bh >> 4, h = bh & 15;
  const int tid = threadIdx.x;
  const int w = tid >> 6, l = tid & 63;
  const int g = w >> 2, wq = w & 3;       // kv-group, q-wave within group
  const int lr = l & 15, lg = l >> 4;
  const int srow8 = l >> 3;
  const int scol = ((l & 7) ^ srow8) * 8; // pre-swizzled source col (elems)
  const u16* Kb = kb + (size_t)bh * TSEQ * 64;
  const u16* Vb = vbT + (size_t)bh * 64 * TSEQ;
  u16* lPw = lP[w];

  auto stage = [&](int buf, int kt) {
#pragma unroll
    for (int is = 0; is < 2; ++is) {
      const int chunk = wq * 2 + is;            // 0..7, 1KB each
      const int row = chunk * 8 + srow8;        // 0..63
      __builtin_amdgcn_global_load_lds(AS1C(Kb + (size_t)(kt * 64 + row) * 64 + scol),
                                       AS3((char*)lK[buf] + chunk * 1024), 16, 0, 0);
      __builtin_amdgcn_global_load_lds(AS1C(Vb + (size_t)row * TSEQ + kt * 64 + scol),
                                       AS3((char*)lV[buf] + chunk * 1024), 16, 0, 0);
    }
  };

  for (int half = 0; half < 2; ++half) {
    const int qt = half ? (TSEQ / 64 - 1 - pair) : pair;
    const int q0 = qt * 64;

    bf16x8 qf[2];
    {
      const u16* qp = qb + ((size_t)bh * TSEQ + q0 + wq * 16 + lr) * 64 + lg * 8;
      qf[0] = *(const bf16x8*)qp;
      qf[1] = *(const bf16x8*)(qp + 32);
    }

    f32x4 oacc[4] = {};
    float lsum = 0.f;

    const int nt = qt + 1;
    const int nit = (nt + 1) >> 1;
    const int ql = wq * 16 + lr;

    __syncthreads();                 // LDS safe to overwrite (prev half done)
    if (g < nt) stage(g * 2, g);
    for (int it = 0; it < nit; ++it) {
      const int cur = it & 1;
      __syncthreads();               // staged buf[cur] visible to whole group
      const int ktn = 2 * (it + 1) + g;
      if (ktn < nt) stage(g * 2 + (cur ^ 1), ktn);
      const int kt = 2 * it + g;
      if (kt < nt) {
        const u16* Kc = lK[g * 2 + cur];
        const u16* Vc = lV[g * 2 + cur];

        // S^T = K Q^T: lane holds S[q=lr][kv = n*16 + lg*4 + r] (log2 domain)
        f32x4 s[4] = {};
        __builtin_amdgcn_s_setprio(1);
#pragma unroll
        for (int n = 0; n < 4; ++n) {
          const int row = n * 16 + lr;
#pragma unroll
          for (int ks = 0; ks < 2; ++ks) {
            const int sl = (ks * 4 + lg) ^ (row & 7);
            bf16x8 kf = *(const bf16x8*)(&Kc[row * 64 + sl * 8]);
            s[n] = mfma16x16(kf, qf[ks], s[n]);
          }
        }
        __builtin_amdgcn_s_setprio(0);

        // P = exp2(s) raw; masked entries zeroed; per-lane partial sums.
        const bool diag = (kt == qt);
#pragma unroll
        for (int n = 0; n < 4; ++n) {
          float pv[4];
#pragma unroll
          for (int r = 0; r < 4; ++r) {
            float p = __builtin_amdgcn_exp2f(s[n][r]);
            if (diag && (n * 16 + lg * 4 + r > ql)) p = 0.f;
            pv[r] = p;
            lsum += p;
          }
          const u32 w0 = pack2bf(pv[0], pv[1]);
          const u32 w1 = pack2bf(pv[2], pv[3]);
          const int phys = (n * 2 + (lg >> 1)) ^ (lr & 7);
          uint2 pk; pk.x = w0; pk.y = w1;
          *(uint2*)(&lPw[lr * 64 + phys * 8 + (lg & 1) * 4]) = pk;
        }

        // O^T += V P^T: lane holds O[q=lr][d = n*16 + lg*4 + r]
        bf16x8 pf[2];
#pragma unroll
        for (int ks = 0; ks < 2; ++ks) {
          const int phys = (ks * 4 + lg) ^ (lr & 7);
          pf[ks] = *(const bf16x8*)(&lPw[lr * 64 + phys * 8]);
        }
        __builtin_amdgcn_s_setprio(1);
#pragma unroll
        for (int n = 0; n < 4; ++n) {
          const int row = n * 16 + lr;
#pragma unroll
          for (int ks = 0; ks < 2; ++ks) {
            const int sl = (ks * 4 + lg) ^ (row & 7);
            bf16x8 vf = *(const bf16x8*)(&Vc[row * 64 + sl * 8]);
            oacc[n] = mfma16x16(vf, pf[ks], oacc[n]);
          }
        }
        __builtin_amdgcn_s_setprio(0);
      }
    }

    // row-total of this group's partial sums (single reduction per q-tile)
    lsum += __shfl_xor(lsum, 16);
    lsum += __shfl_xor(lsum, 32);

    // merge the two groups' (O, l) through LDS — no exp scaling needed
    __syncthreads();                  // all compute done; K/V LDS reusable
    float* mO = (float*)&lK[0][0];    // 4 waves x 1024 f32 = 16KB
    float* mL = (float*)&lV[0][0];    // 4 waves x 16 f32
    if (g == 1) {
#pragma unroll
      for (int n = 0; n < 4; ++n)
#pragma unroll
        for (int r = 0; r < 4; ++r) {
          const int d = n * 16 + lg * 4 + r;
          mO[wq * 1024 + d * 16 + lr] = oacc[n][r];
        }
      if (lg == 0) mL[wq * 16 + lr] = lsum;
    }
    __syncthreads();
    if (g == 0) {
      const float rl = 1.f / (lsum + mL[wq * 16 + lr]);
      const int q = q0 + wq * 16 + lr;
#pragma unroll
      for (int n = 0; n < 4; ++n) {
        ushort4 ov;
#pragma unroll
        for (int r = 0; r < 4; ++r) {
          const int d = n * 16 + lg * 4 + r;
          const float o = oacc[n][r] + mO[wq * 1024 + d * 16 + lr];
          ((u16*)&ov)[r] = f2bf(o * rl);
        }
        *(ushort4*)(&ob[(size_t)(b * TSEQ + q) * DM + h * 64 + n * 16 + lg * 4]) = ov;
      }
    }
  }
}

// ---------------- launch ----------------
extern "C" void kernel_launch(void* const* d_in, const int* in_sizes, int n_in,
                              void* d_out, int out_size, void* d_ws, size_t ws_size,
                              hipStream_t stream) {
  const float* x    = (const float*)d_in[0];
  const float* Wqkv = (const float*)d_in[1];
  const float* Wo   = (const float*)d_in[2];
  float* out = (float*)d_out;

  char* ws = (char*)d_ws;
  u16* xb    = (u16*)ws; ws += (size_t)MROWS * DM * 2;
  u16* wqkvb = (u16*)ws; ws += (size_t)3 * DM * DM * 2;
  u16* wob   = (u16*)ws; ws += (size_t)DM * DM * 2;
  u16* qb    = (u16*)ws; ws += (size_t)BB * NHEADS * TSEQ * HDIM * 2;
  u16* kb    = (u16*)ws; ws += (size_t)BB * NHEADS * TSEQ * HDIM * 2;
  u16* vbT   = (u16*)ws; ws += (size_t)BB * NHEADS * TSEQ * HDIM * 2;
  u16* ob    = (u16*)ws; ws += (size_t)MROWS * DM * 2;

  cast_all<<<2048, 256, 0, stream>>>(x, Wqkv, Wo, xb, wqkvb, wob);

  gemm_qkv<<<dim3(3 * DM / 128, MROWS / 128), 256, 0, stream>>>(
      xb, wqkvb, qb, kb, vbT, MROWS, 3 * DM, DM);

  attn_fwd<<<512, 512, 0, stream>>>(qb, kb, vbT, ob);

  gemm_bt64<<<dim3(DM / 128, MROWS / 64), 256, 0, stream>>>(
      ob, wob, out, MROWS, DM, DM);
}

// Round 15
// 98.986 us; speedup vs baseline: 1.4646x; 1.0158x over previous
//
#include <hip/hip_runtime.h>
#include <hip/hip_bf16.h>
#include <cstdint>

#define NHEADS 16
#define HDIM 64
#define BB 2
#define TSEQ 2048
#define DM 1024
#define MROWS (BB*TSEQ)   // 4096

typedef unsigned short u16;
typedef unsigned int u32;
typedef __bf16 bf16x8 __attribute__((ext_vector_type(8)));
typedef float f32x4 __attribute__((ext_vector_type(4)));

#define AS1C(p) ((const __attribute__((address_space(1))) u32*)(p))
#define AS3(p)  ((__attribute__((address_space(3))) u32*)(p))

static __device__ __forceinline__ u16 f2bf(float f) {
  return __builtin_bit_cast(u16, __float2bfloat16(f));
}
static __device__ __forceinline__ float bf2f(u16 u) {
  return __bfloat162float(__builtin_bit_cast(__hip_bfloat16, u));
}
// pack two non-NaN floats to bf16 pair (round-half-up, max rel err 2^-8)
static __device__ __forceinline__ u32 pack2bf(float a, float b) {
  const u32 ua = __builtin_bit_cast(u32, a) + 0x8000u;
  const u32 ub = __builtin_bit_cast(u32, b) + 0x8000u;
  return (ua >> 16) | (ub & 0xFFFF0000u);
}
static __device__ __forceinline__ f32x4 mfma16x16(bf16x8 a, bf16x8 b, f32x4 c) {
  return __builtin_amdgcn_mfma_f32_16x16x32_bf16(a, b, c, 0, 0, 0);
}

// ---------------- fused cast fp32 -> bf16 for x, W_qkv, W_o ----------------
#define N4_X   (MROWS * DM / 4)
#define N4_WQ  (3 * DM * DM / 4)
#define N4_WO  (DM * DM / 4)
__global__ __launch_bounds__(256) void cast_all(const float* __restrict__ x,
                                                const float* __restrict__ wq,
                                                const float* __restrict__ wo,
                                                u16* __restrict__ xb,
                                                u16* __restrict__ wqb,
                                                u16* __restrict__ wob) {
  int i = blockIdx.x * 256 + threadIdx.x;
  const int stride = gridDim.x * 256;
  for (; i < N4_X + N4_WQ + N4_WO; i += stride) {
    const float4* src; u16* dst; int j;
    if (i < N4_X)            { src = (const float4*)x;  dst = xb;  j = i; }
    else if (i < N4_X + N4_WQ) { src = (const float4*)wq; dst = wqb; j = i - N4_X; }
    else                     { src = (const float4*)wo; dst = wob; j = i - N4_X - N4_WQ; }
    float4 v = src[j];
    ushort4 o;
    o.x = f2bf(v.x); o.y = f2bf(v.y); o.z = f2bf(v.z); o.w = f2bf(v.w);
    ((ushort4*)dst)[j] = o;
  }
}

// ------- GEMM1 fused: qkv = x @ Wqkv^T, epilogue does RoPE + reshape -------
// 128x128 tile, 2-phase double-buffer. For q/k blocks the B-tile rows are
// PERMUTED at the staging source (even output-cols d into tile-cols 0..31,
// odd into 32..63, per 64-col half), so the RoPE pair (2p, 2p+1) lands in
// the SAME lane as fragments n and n+2: no cross-lane shuffle, one sincos
// per pair (used for both outputs), one packed 4B store per pair.
//  q/k blocks: RoPE (q pre-scaled by (1/8)*log2e) -> [bh][t][64].
//  v blocks: direct transposed write to vbT[bh][64][TSEQ].
__global__ __launch_bounds__(256, 2) void gemm_qkv(const u16* __restrict__ A,
                                                   const u16* __restrict__ Bm,
                                                   u16* __restrict__ qb,
                                                   u16* __restrict__ kbuf,
                                                   u16* __restrict__ vbT,
                                                   int M, int N, int K) {
  __shared__ u16 lA[2][128 * 32];
  __shared__ u16 lB[2][128 * 32];
  const int tid = threadIdx.x;
  const int w = tid >> 6, l = tid & 63;
  const int wr = w >> 1, wc = w & 1;
  int bid = blockIdx.y * gridDim.x + blockIdx.x;
  const int cpx = (gridDim.x * gridDim.y) >> 3;
  bid = (bid & 7) * cpx + (bid >> 3);
  const int bx = bid % gridDim.x, by = bid / gridDim.x;
  const int brow = by * 128, bcol = bx * 128;
  const int lr = l & 15, lg = l >> 4;
  const bool isqk = (bcol < 2048);

  const int srow = l >> 2;
  const int scol = (((l & 3) ^ (srow & 3)) * 8);

  auto stage = [&](int buf, int k0) {
#pragma unroll
    for (int is = 0; is < 2; ++is) {
      const int chunk = w * 2 + is;
      const int row = chunk * 16 + srow;
      __builtin_amdgcn_global_load_lds(AS1C(A + (size_t)(brow + row) * K + k0 + scol),
                                       AS3((char*)lA[buf] + chunk * 1024), 16, 0, 0);
      // B-row permutation for q/k blocks: tile-row r holds global col
      // bcol + perm(r); perm splits each 64-half into evens then odds.
      int prow = row;
      if (isqk) {
        const int r63 = row & 63;
        prow = (row & 64) | ((r63 < 32) ? (2 * r63) : (2 * (r63 - 32) + 1));
      }
      __builtin_amdgcn_global_load_lds(AS1C(Bm + (size_t)(bcol + prow) * K + k0 + scol),
                                       AS3((char*)lB[buf] + chunk * 1024), 16, 0, 0);
    }
  };

  f32x4 acc[4][4] = {};
  const int nk = K >> 5;
  stage(0, 0);
  for (int kk = 0; kk < nk; ++kk) {
    const int cur = kk & 1;
    __syncthreads();
    if (kk + 1 < nk) stage(cur ^ 1, (kk + 1) << 5);
    bf16x8 af[4], bfr[4];
#pragma unroll
    for (int m = 0; m < 4; ++m) {
      const int row = wr * 64 + m * 16 + lr;
      const int sl = lg ^ (row & 3);
      af[m] = *(const bf16x8*)(&lA[cur][row * 32 + sl * 8]);
    }
#pragma unroll
    for (int n = 0; n < 4; ++n) {
      const int row = wc * 64 + n * 16 + lr;
      const int sl = lg ^ (row & 3);
      bfr[n] = *(const bf16x8*)(&lB[cur][row * 32 + sl * 8]);
    }
#pragma unroll
    for (int m = 0; m < 4; ++m)
#pragma unroll
      for (int n = 0; n < 4; ++n)
        acc[m][n] = mfma16x16(af[m], bfr[n], acc[m][n]);
  }

  const float C = -0.4152410118609203f;   // -log2(10000)/32
  const float QS = 0.125f * 1.44269504088896341f;
  const float R2PI = 0.15915494309189535f;

  if (isqk) {          // q or k block: register-local RoPE pair
    const bool isq = (bcol < 1024);
    const int head = ((bcol + wc * 64) >> 6) & 15;
    u16* dst = isq ? qb : kbuf;
#pragma unroll
    for (int n = 0; n < 2; ++n) {
      const int p = n * 16 + lr;          // pair index; d = 2p
      const float inv = exp2f((float)p * C);
#pragma unroll
      for (int m = 0; m < 4; ++m)
#pragma unroll
        for (int r = 0; r < 4; ++r) {
          const int row = brow + wr * 64 + m * 16 + lg * 4 + r;
          const int t = row & (TSEQ - 1), b = row >> 11;
          const float rev = __builtin_amdgcn_fractf((float)t * inv * R2PI);
          float sn = __builtin_amdgcn_sinf(rev);
          float cs = __builtin_amdgcn_cosf(rev);
          if (isq) { sn *= QS; cs *= QS; }
          const float e = acc[m][n][r];     // even d = 2p
          const float o = acc[m][n + 2][r]; // odd  d = 2p+1
          const u32 pk = pack2bf(e * cs - o * sn, e * sn + o * cs);
          *(u32*)(&dst[(((size_t)(b * 16 + head)) * TSEQ + t) * 64 + 2 * p]) = pk;
        }
    }
  } else {             // v block: transposed write to vbT[bh][64][TSEQ]
    const int head = (((bcol - 2048) + wc * 64) >> 6) & 15;
#pragma unroll
    for (int n = 0; n < 4; ++n) {
      const int d = n * 16 + lr;
#pragma unroll
      for (int m = 0; m < 4; ++m) {
        const int row0 = brow + wr * 64 + m * 16 + lg * 4;
        const int t = row0 & (TSEQ - 1), b = row0 >> 11;
        uint2 pk;
        pk.x = pack2bf(acc[m][n][0], acc[m][n][1]);
        pk.y = pack2bf(acc[m][n][2], acc[m][n][3]);
        *(uint2*)(&vbT[((size_t)(b * 16 + head) * 64 + d) * TSEQ + t]) = pk;
      }
    }
  }
}

// ------------- bf16 GEMM 64x128 tile (fp32 out) — output projection --------
__global__ __launch_bounds__(256, 2) void gemm_bt64(const u16* __restrict__ A,
                                                    const u16* __restrict__ Bm,
                                                    float* __restrict__ Cf,
                                                    int M, int N, int K) {
  __shared__ u16 lA[2][64 * 32];
  __shared__ u16 lB[2][128 * 32];
  const int tid = threadIdx.x;
  const int w = tid >> 6, l = tid & 63;
  const int wr = w >> 1, wc = w & 1;
  int bid = blockIdx.y * gridDim.x + blockIdx.x;
  const int cpx = (gridDim.x * gridDim.y) >> 3;
  bid = (bid & 7) * cpx + (bid >> 3);
  const int bx = bid % gridDim.x, by = bid / gridDim.x;
  const int brow = by * 64, bcol = bx * 128;
  const int lr = l & 15, lg = l >> 4;

  const int srow = l >> 2;
  const int scol = (((l & 3) ^ (srow & 3)) * 8);

  auto stage = [&](int buf, int k0) {
    {
      const int row = w * 16 + srow;
      __builtin_amdgcn_global_load_lds(AS1C(A + (size_t)(brow + row) * K + k0 + scol),
                                       AS3((char*)lA[buf] + w * 1024), 16, 0, 0);
    }
#pragma unroll
    for (int is = 0; is < 2; ++is) {
      const int chunk = w * 2 + is;
      const int row = chunk * 16 + srow;
      __builtin_amdgcn_global_load_lds(AS1C(Bm + (size_t)(bcol + row) * K + k0 + scol),
                                       AS3((char*)lB[buf] + chunk * 1024), 16, 0, 0);
    }
  };

  f32x4 acc[2][4] = {};
  const int nk = K >> 5;
  stage(0, 0);
  for (int kk = 0; kk < nk; ++kk) {
    const int cur = kk & 1;
    __syncthreads();
    if (kk + 1 < nk) stage(cur ^ 1, (kk + 1) << 5);
    bf16x8 af[2], bfr[4];
#pragma unroll
    for (int m = 0; m < 2; ++m) {
      const int row = wr * 32 + m * 16 + lr;
      const int sl = lg ^ (row & 3);
      af[m] = *(const bf16x8*)(&lA[cur][row * 32 + sl * 8]);
    }
#pragma unroll
    for (int n = 0; n < 4; ++n) {
      const int row = wc * 64 + n * 16 + lr;
      const int sl = lg ^ (row & 3);
      bfr[n] = *(const bf16x8*)(&lB[cur][row * 32 + sl * 8]);
    }
#pragma unroll
    for (int m = 0; m < 2; ++m)
#pragma unroll
      for (int n = 0; n < 4; ++n)
        acc[m][n] = mfma16x16(af[m], bfr[n], acc[m][n]);
  }
#pragma unroll
  for (int m = 0; m < 2; ++m)
#pragma unroll
    for (int n = 0; n < 4; ++n)
#pragma unroll
      for (int r = 0; r < 4; ++r) {
        const int row = brow + wr * 32 + m * 16 + lg * 4 + r;
        const int col = bcol + wc * 64 + n * 16 + lr;
        Cf[(size_t)row * N + col] = acc[m][n][r];
      }
}

// ---------------- causal flash attention (R5-proven configuration) --------
__global__ __launch_bounds__(512, 4) void attn_fwd(const u16* __restrict__ qb,
                                                   const u16* __restrict__ kb,
                                                   const u16* __restrict__ vbT,
                                                   u16* __restrict__ ob) {
  __shared__ u16 lK[4][64 * 64];
  __shared__ u16 lV[4][64 * 64];
  __shared__ u16 lP[8][16 * 64];
  const int hw = blockIdx.x;
  const int logical = (hw & 7) * 64 + (hw >> 3);  // 8 XCDs x 64 blocks
  const int bh = logical >> 4;            // 4 consecutive heads per XCD
  const int pair = logical & 15;
  const int b = bh >> 4, h = bh & 15;
  const int tid = threadIdx.x;
  const int w = tid >> 6, l = tid & 63;
  const int g = w >> 2, wq = w & 3;       // kv-group, q-wave within group
  const int lr = l & 15, lg = l >> 4;
  const int srow8 = l >> 3;
  const int scol = ((l & 7) ^ srow8) * 8; // pre-swizzled source col (elems)
  const u16* Kb = kb + (size_t)bh * TSEQ * 64;
  const u16* Vb = vbT + (size_t)bh * 64 * TSEQ;
  u16* lPw = lP[w];

  auto stage = [&](int buf, int kt) {
#pragma unroll
    for (int is = 0; is < 2; ++is) {
      const int chunk = wq * 2 + is;            // 0..7, 1KB each
      const int row = chunk * 8 + srow8;        // 0..63
      __builtin_amdgcn_global_load_lds(AS1C(Kb + (size_t)(kt * 64 + row) * 64 + scol),
                                       AS3((char*)lK[buf] + chunk * 1024), 16, 0, 0);
      __builtin_amdgcn_global_load_lds(AS1C(Vb + (size_t)row * TSEQ + kt * 64 + scol),
                                       AS3((char*)lV[buf] + chunk * 1024), 16, 0, 0);
    }
  };

  for (int half = 0; half < 2; ++half) {
    const int qt = half ? (TSEQ / 64 - 1 - pair) : pair;
    const int q0 = qt * 64;

    bf16x8 qf[2];
    {
      const u16* qp = qb + ((size_t)bh * TSEQ + q0 + wq * 16 + lr) * 64 + lg * 8;
      qf[0] = *(const bf16x8*)qp;
      qf[1] = *(const bf16x8*)(qp + 32);
    }

    f32x4 oacc[4] = {};
    float lsum = 0.f;

    const int nt = qt + 1;
    const int nit = (nt + 1) >> 1;
    const int ql = wq * 16 + lr;

    __syncthreads();                 // LDS safe to overwrite (prev half done)
    if (g < nt) stage(g * 2, g);
    for (int it = 0; it < nit; ++it) {
      const int cur = it & 1;
      __syncthreads();               // staged buf[cur] visible to whole group
      const int ktn = 2 * (it + 1) + g;
      if (ktn < nt) stage(g * 2 + (cur ^ 1), ktn);
      const int kt = 2 * it + g;
      if (kt < nt) {
        const u16* Kc = lK[g * 2 + cur];
        const u16* Vc = lV[g * 2 + cur];

        // S^T = K Q^T: lane holds S[q=lr][kv = n*16 + lg*4 + r] (log2 domain)
        f32x4 s[4] = {};
        __builtin_amdgcn_s_setprio(1);
#pragma unroll
        for (int n = 0; n < 4; ++n) {
          const int row = n * 16 + lr;
#pragma unroll
          for (int ks = 0; ks < 2; ++ks) {
            const int sl = (ks * 4 + lg) ^ (row & 7);
            bf16x8 kf = *(const bf16x8*)(&Kc[row * 64 + sl * 8]);
            s[n] = mfma16x16(kf, qf[ks], s[n]);
          }
        }
        __builtin_amdgcn_s_setprio(0);

        // P = exp2(s) raw; masked entries zeroed; per-lane partial sums.
        const bool diag = (kt == qt);
#pragma unroll
        for (int n = 0; n < 4; ++n) {
          float pv[4];
#pragma unroll
          for (int r = 0; r < 4; ++r) {
            float p = __builtin_amdgcn_exp2f(s[n][r]);
            if (diag && (n * 16 + lg * 4 + r > ql)) p = 0.f;
            pv[r] = p;
            lsum += p;
          }
          const u32 w0 = pack2bf(pv[0], pv[1]);
          const u32 w1 = pack2bf(pv[2], pv[3]);
          const int phys = (n * 2 + (lg >> 1)) ^ (lr & 7);
          uint2 pk; pk.x = w0; pk.y = w1;
          *(uint2*)(&lPw[lr * 64 + phys * 8 + (lg & 1) * 4]) = pk;
        }

        // O^T += V P^T: lane holds O[q=lr][d = n*16 + lg*4 + r]
        bf16x8 pf[2];
#pragma unroll
        for (int ks = 0; ks < 2; ++ks) {
          const int phys = (ks * 4 + lg) ^ (lr & 7);
          pf[ks] = *(const bf16x8*)(&lPw[lr * 64 + phys * 8]);
        }
        __builtin_amdgcn_s_setprio(1);
#pragma unroll
        for (int n = 0; n < 4; ++n) {
          const int row = n * 16 + lr;
#pragma unroll
          for (int ks = 0; ks < 2; ++ks) {
            const int sl = (ks * 4 + lg) ^ (row & 7);
            bf16x8 vf = *(const bf16x8*)(&Vc[row * 64 + sl * 8]);
            oacc[n] = mfma16x16(vf, pf[ks], oacc[n]);
          }
        }
        __builtin_amdgcn_s_setprio(0);
      }
    }

    // row-total of this group's partial sums (single reduction per q-tile)
    lsum += __shfl_xor(lsum, 16);
    lsum += __shfl_xor(lsum, 32);

    // merge the two groups' (O, l) through LDS — no exp scaling needed
    __syncthreads();                  // all compute done; K/V LDS reusable
    float* mO = (float*)&lK[0][0];    // 4 waves x 1024 f32 = 16KB
    float* mL = (float*)&lV[0][0];    // 4 waves x 16 f32
    if (g == 1) {
#pragma unroll
      for (int n = 0; n < 4; ++n)
#pragma unroll
        for (int r = 0; r < 4; ++r) {
          const int d = n * 16 + lg * 4 + r;
          mO[wq * 1024 + d * 16 + lr] = oacc[n][r];
        }
      if (lg == 0) mL[wq * 16 + lr] = lsum;
    }
    __syncthreads();
    if (g == 0) {
      const float rl = 1.f / (lsum + mL[wq * 16 + lr]);
      const int q = q0 + wq * 16 + lr;
#pragma unroll
      for (int n = 0; n < 4; ++n) {
        ushort4 ov;
#pragma unroll
        for (int r = 0; r < 4; ++r) {
          const int d = n * 16 + lg * 4 + r;
          const float o = oacc[n][r] + mO[wq * 1024 + d * 16 + lr];
          ((u16*)&ov)[r] = f2bf(o * rl);
        }
        *(ushort4*)(&ob[(size_t)(b * TSEQ + q) * DM + h * 64 + n * 16 + lg * 4]) = ov;
      }
    }
  }
}

// ---------------- launch ----------------
extern "C" void kernel_launch(void* const* d_in, const int* in_sizes, int n_in,
                              void* d_out, int out_size, void* d_ws, size_t ws_size,
                              hipStream_t stream) {
  const float* x    = (const float*)d_in[0];
  const float* Wqkv = (const float*)d_in[1];
  const float* Wo   = (const float*)d_in[2];
  float* out = (float*)d_out;

  char* ws = (char*)d_ws;
  u16* xb    = (u16*)ws; ws += (size_t)MROWS * DM * 2;
  u16* wqkvb = (u16*)ws; ws += (size_t)3 * DM * DM * 2;
  u16* wob   = (u16*)ws; ws += (size_t)DM * DM * 2;
  u16* qb    = (u16*)ws; ws += (size_t)BB * NHEADS * TSEQ * HDIM * 2;
  u16* kb    = (u16*)ws; ws += (size_t)BB * NHEADS * TSEQ * HDIM * 2;
  u16* vbT   = (u16*)ws; ws += (size_t)BB * NHEADS * TSEQ * HDIM * 2;
  u16* ob    = (u16*)ws; ws += (size_t)MROWS * DM * 2;

  cast_all<<<2048, 256, 0, stream>>>(x, Wqkv, Wo, xb, wqkvb, wob);

  gemm_qkv<<<dim3(3 * DM / 128, MROWS / 128), 256, 0, stream>>>(
      xb, wqkvb, qb, kb, vbT, MROWS, 3 * DM, DM);

  attn_fwd<<<512, 512, 0, stream>>>(qb, kb, vbT, ob);

  gemm_bt64<<<dim3(DM / 128, MROWS / 64), 256, 0, stream>>>(
      ob, wob, out, MROWS, DM, DM);
}